// Round 5
// baseline (407.173 us; speedup 1.0000x reference)
//
#include <hip/hip_runtime.h>
#include <math.h>

#define BB 8
#define NN 2048
#define SS 16
#define CC 32
#define DD 128

typedef unsigned short u16;
typedef __attribute__((ext_vector_type(8))) short bf16x8;
typedef __attribute__((ext_vector_type(4))) float f32x4;

__device__ inline u16 f2bf(float f) {
    union { float f; unsigned u; } c; c.f = f;
    unsigned r = c.u + 0x7fff + ((c.u >> 16) & 1);   // round-to-nearest-even
    return (u16)(r >> 16);
}
__device__ inline float bf2f(u16 h) {
    union { unsigned u; float f; } c; c.u = ((unsigned)h) << 16;
    return c.f;
}
__device__ inline u16 f2h(float f) {
    union { _Float16 h; u16 u; } c; c.h = (_Float16)f;
    return c.u;
}
__device__ inline float h2f(u16 u) {
    union { _Float16 h; u16 v; } c; c.v = u;
    return (float)c.h;
}
__device__ inline float clamp01(float v) { return fminf(fmaxf(v, 0.f), 1.f); }

// ---------------- K1: merged prep: bias tables + wcomb + wlt ---------------
__global__ __launch_bounds__(256) void prep_kernel(const float* __restrict__ Astat,
                                                   const int* __restrict__ Mm,
                                                   const float* __restrict__ Wproj,
                                                   const float* __restrict__ Wq,
                                                   const float* __restrict__ Wk,
                                                   const float* __restrict__ Wl,
                                                   u16* __restrict__ lgh,
                                                   u16* __restrict__ am,
                                                   float* __restrict__ Wpq,
                                                   float* __restrict__ Wpk,
                                                   u16* __restrict__ WlT) {
    int bx = blockIdx.x;
    if (bx < 4096) {
        size_t g = ((size_t)bx * 256 + threadIdx.x) * 4;   // 4194304 total
        float4 a4 = *(const float4*)&Astat[g];
        int4 m4 = *(const int4*)&Mm[g];
        float a[4] = {a4.x, a4.y, a4.z, a4.w};
        int mm[4] = {m4.x, m4.y, m4.z, m4.w};
        ushort4 lo, ao;
        u16 lg[4], ab[4];
#pragma unroll
        for (int j = 0; j < 4; ++j) {
            float p = fminf(fmaxf(a[j], 1e-3f), 1.f - 1e-3f);
            float l = __logf(p / (1.f - p));          // ETA = 1.0
            lg[j] = mm[j] ? f2h(l) : (u16)0xFC00;     // -inf f16 when masked
            ab[j] = mm[j] ? f2bf(a[j]) : (u16)0;
        }
        lo.x = lg[0]; lo.y = lg[1]; lo.z = lg[2]; lo.w = lg[3];
        ao.x = ab[0]; ao.y = ab[1]; ao.z = ab[2]; ao.w = ab[3];
        *(ushort4*)&lgh[g] = lo;
        *(ushort4*)&am[g] = ao;
    } else if (bx < 4128) {
        int i = (bx - 4096) * 256 + threadIdx.x;      // 8192 outputs
        int d = i & 127;
        int c = (i >> 7) & 31;
        int mat = i >> 12;
        const float* Wt = mat ? Wk : Wq;
        float acc = 0.f;
#pragma unroll 4
        for (int e = 0; e < DD; ++e)
            acc = fmaf(Wproj[c * DD + e], Wt[e * DD + d], acc);
        (mat ? Wpk : Wpq)[c * DD + d] = acc;
    } else {
        int i = (bx - 4128) * 256 + threadIdx.x;      // 16384 outputs
        int dp = i >> 7, d = i & 127;
        WlT[dp * DD + d] = f2bf(Wl[d * DD + dp]);
    }
}

// ---------------- K3: fused pool + Hn/Q/K projections, emitted bf16 --------
__global__ __launch_bounds__(256) void proj3_kernel(const float* __restrict__ X,
                                                    const float* __restrict__ Msk,
                                                    const float* __restrict__ Wproj,
                                                    const float* __restrict__ Wpq,
                                                    const float* __restrict__ Wpk,
                                                    u16* __restrict__ HnT,
                                                    u16* __restrict__ Qb,
                                                    u16* __restrict__ Kb) {
    __shared__ float wp[CC * DD], wq[CC * DD], wk[CC * DD];
    __shared__ float xs[CC * 36];
    int t = threadIdx.x;
    for (int i = t; i < CC * DD; i += 256) {
        wp[i] = Wproj[i];
        wq[i] = Wpq[i];
        wk[i] = Wpk[i];
    }
    int rbase = blockIdx.x * 32;
    {   // masked temporal mean pooling: thread = (row, 4-col group)
        int row = t >> 3, cg = t & 7;
        const float* xrow = X + ((size_t)(rbase + row) * SS) * CC + cg * 4;
        const float* mrow = Msk + (size_t)(rbase + row) * SS;
        float4 acc = make_float4(0.f, 0.f, 0.f, 0.f);
        float msum = 0.f;
#pragma unroll
        for (int s = 0; s < SS; ++s) {
            float mv = mrow[s];
            float4 xv = *(const float4*)&xrow[s * CC];
            msum += mv;
            acc.x = fmaf(xv.x, mv, acc.x);
            acc.y = fmaf(xv.y, mv, acc.y);
            acc.z = fmaf(xv.z, mv, acc.z);
            acc.w = fmaf(xv.w, mv, acc.w);
        }
        float inv = 1.f / fmaxf(msum, 1.0f);
        xs[(cg * 4 + 0) * 36 + row] = acc.x * inv;
        xs[(cg * 4 + 1) * 36 + row] = acc.y * inv;
        xs[(cg * 4 + 2) * 36 + row] = acc.z * inv;
        xs[(cg * 4 + 3) * 36 + row] = acc.w * inv;
    }
    __syncthreads();

    int col = t & 127;
    int g = t >> 7;
    float ah[16], aq[16], ak[16];
#pragma unroll
    for (int i = 0; i < 16; ++i) { ah[i] = 0.f; aq[i] = 0.f; ak[i] = 0.f; }

#pragma unroll 4
    for (int k = 0; k < CC; ++k) {
        float wpv = wp[k * DD + col], wqv = wq[k * DD + col], wkv = wk[k * DD + col];
        const float4* xp = (const float4*)&xs[k * 36 + g * 16];
        float4 a0 = xp[0], a1 = xp[1], a2 = xp[2], a3 = xp[3];
        float xv[16] = {a0.x, a0.y, a0.z, a0.w, a1.x, a1.y, a1.z, a1.w,
                        a2.x, a2.y, a2.z, a2.w, a3.x, a3.y, a3.z, a3.w};
#pragma unroll
        for (int i = 0; i < 16; ++i) {
            ah[i] = fmaf(xv[i], wpv, ah[i]);
            aq[i] = fmaf(xv[i], wqv, aq[i]);
            ak[i] = fmaf(xv[i], wkv, ak[i]);
        }
    }
    const float scale = 0.08838834764831845f;     // 1/sqrt(128) folded into Q
#pragma unroll
    for (int i = 0; i < 16; ++i) {
        size_t row = (size_t)(rbase + g * 16 + i);
        Qb[row * DD + col] = f2bf(aq[i] * scale);
        Kb[row * DD + col] = f2bf(ak[i]);
    }
    int b = rbase >> 11;
    int n0 = (rbase & (NN - 1)) + g * 16;
    u16* hp = HnT + (size_t)b * DD * NN + (size_t)col * NN + n0;
    unsigned pk[8];
#pragma unroll
    for (int i = 0; i < 8; ++i)
        pk[i] = (unsigned)f2bf(ah[2 * i]) | ((unsigned)f2bf(ah[2 * i + 1]) << 16);
    *(uint4*)&hp[0] = make_uint4(pk[0], pk[1], pk[2], pk[3]);
    *(uint4*)&hp[8] = make_uint4(pk[4], pk[5], pk[6], pk[7]);
}

// ---------------- K4: stats — QK^T row partials (no e materialization) -----
// grid (cs=4, rt=64, b=8) = 2048 blocks; block: 32 rows x 512 cols (4 tiles),
// K-tile staging register-prefetched.
#define LQT 136
__global__ __launch_bounds__(256) void stats_kernel(
        const u16* __restrict__ Qb, const u16* __restrict__ Kb,
        const u16* __restrict__ lgh, const u16* __restrict__ am,
        const float* __restrict__ rel,
        float* __restrict__ part) {
    __shared__ u16 Qs[32 * LQT];
    __shared__ u16 Ks[128 * LQT];
    __shared__ float redE[128], redR[128], redA[128];
    int cs = blockIdx.x, rt = blockIdx.y, b = blockIdx.z;
    int R0 = rt * 32, C0 = cs * 512;
    int t = threadIdx.x;
    int lane = t & 63, w = t >> 6, q = lane >> 4, r16 = lane & 15;

    const u16* Qg = Qb + ((size_t)b * NN + R0) * DD;
#pragma unroll
    for (int rep = 0; rep < 2; ++rep) {
        int e = rep * 256 + t;
        int row = e >> 4, seg = e & 15;
        *(uint4*)&Qs[row * LQT + seg * 8] = *(const uint4*)&Qg[row * DD + seg * 8];
    }
    const u16* Kg = Kb + (size_t)b * NN * DD;
    int colr = t >> 4, seg8 = (t & 15) * 8;       // staging slot (8 reps of 32 rows)
    float ER[2][4], LR[2][4], LA[2][4];
#pragma unroll
    for (int i = 0; i < 2; ++i)
#pragma unroll
        for (int r = 0; r < 4; ++r) { ER[i][r] = 0.f; LR[i][r] = 0.f; LA[i][r] = 0.f; }

    // prologue prefetch: tile ct=0
    uint4 pk[8];
#pragma unroll
    for (int rep = 0; rep < 8; ++rep)
        pk[rep] = *(const uint4*)&Kg[(size_t)(C0 + rep * 16 + colr) * DD + seg8];

    for (int ct = 0; ct < 4; ++ct) {
        __syncthreads();                          // prev MFMA reads done
#pragma unroll
        for (int rep = 0; rep < 8; ++rep)
            *(uint4*)&Ks[(rep * 16 + colr) * LQT + seg8] = pk[rep];
        if (ct < 3) {
#pragma unroll
            for (int rep = 0; rep < 8; ++rep)
                pk[rep] = *(const uint4*)&Kg[(size_t)(C0 + (ct + 1) * 128 + rep * 16 + colr) * DD + seg8];
        }
        __syncthreads();
        f32x4 acc[2][2];
#pragma unroll
        for (int i = 0; i < 2; ++i)
#pragma unroll
            for (int j = 0; j < 2; ++j)
                acc[i][j] = (f32x4){0.f, 0.f, 0.f, 0.f};
#pragma unroll
        for (int ksp = 0; ksp < 4; ++ksp) {
            int ko = ksp * 32 + q * 8;
            bf16x8 a0 = *(const bf16x8*)&Qs[r16 * LQT + ko];
            bf16x8 a1 = *(const bf16x8*)&Qs[(16 + r16) * LQT + ko];
            bf16x8 b0 = *(const bf16x8*)&Ks[(w * 32 + r16) * LQT + ko];
            bf16x8 b1 = *(const bf16x8*)&Ks[(w * 32 + 16 + r16) * LQT + ko];
            acc[0][0] = __builtin_amdgcn_mfma_f32_16x16x32_bf16(a0, b0, acc[0][0], 0, 0, 0);
            acc[0][1] = __builtin_amdgcn_mfma_f32_16x16x32_bf16(a0, b1, acc[0][1], 0, 0, 0);
            acc[1][0] = __builtin_amdgcn_mfma_f32_16x16x32_bf16(a1, b0, acc[1][0], 0, 0, 0);
            acc[1][1] = __builtin_amdgcn_mfma_f32_16x16x32_bf16(a1, b1, acc[1][1], 0, 0, 0);
        }
        int m0 = C0 + ct * 128 + w * 32;
        float rm0 = clamp01(rel[b * NN + m0 + r16]);
        float rm1 = clamp01(rel[b * NN + m0 + 16 + r16]);
#pragma unroll
        for (int i = 0; i < 2; ++i)
#pragma unroll
            for (int r = 0; r < 4; ++r) {
                int n = R0 + i * 16 + q * 4 + r;
                const u16* lrow = lgh + (size_t)n * NN + m0;
                const u16* arow = am + (size_t)n * NN + m0;
                float lg0 = h2f(lrow[r16]), lg1 = h2f(lrow[16 + r16]);
                float a0 = bf2f(arow[r16]), a1 = bf2f(arow[16 + r16]);
                float e0 = __expf(acc[i][0][r] + lg0);        // masked: -inf -> 0
                float e1 = __expf(acc[i][1][r] + lg1);
                ER[i][r] += e0 + e1;
                LR[i][r] = fmaf(e0, rm0, fmaf(e1, rm1, LR[i][r]));
                LA[i][r] = fmaf(a0, rm0, fmaf(a1, rm1, LA[i][r]));
            }
    }
#pragma unroll
    for (int i = 0; i < 2; ++i)
#pragma unroll
        for (int r = 0; r < 4; ++r) {
            float e = ER[i][r], lr = LR[i][r], la = LA[i][r];
#pragma unroll
            for (int off = 1; off < 16; off <<= 1) {
                e += __shfl_xor(e, off);
                lr += __shfl_xor(lr, off);
                la += __shfl_xor(la, off);
            }
            if (r16 == 0) {
                int row = i * 16 + q * 4 + r;
                redE[w * 32 + row] = e;
                redR[w * 32 + row] = lr;
                redA[w * 32 + row] = la;
            }
        }
    __syncthreads();
    if (t < 32) {
        float es = redE[t] + redE[32 + t] + redE[64 + t] + redE[96 + t];
        float lr = redR[t] + redR[32 + t] + redR[64 + t] + redR[96 + t];
        float la = redA[t] + redA[32 + t] + redA[64 + t] + redA[96 + t];
        float* p = part + ((size_t)((b * 64 + rt) * 4 + cs)) * 96;
        p[t] = es;
        p[32 + t] = lr;
        p[64 + t] = la;
    }
}

// ---------------- K5: recompute-e GEMM1 + A_fuse + coef + W_lin/LN tail ----
#define LPT 72
#define LWT 136
__global__ __launch_bounds__(512) void prop_kernel(
        const u16* __restrict__ Qb, const u16* __restrict__ Kb,
        const u16* __restrict__ lgh, const u16* __restrict__ am,
        const float* __restrict__ part, const float* __restrict__ rel,
        const u16* __restrict__ HnT, const u16* __restrict__ WlT,
        const float* __restrict__ s1, const float* __restrict__ b1,
        const float* __restrict__ s2, const float* __restrict__ b2,
        float* __restrict__ Af, float* __restrict__ out) {
    __shared__ union {
        struct { u16 Qs[32 * LQT]; u16 Ks[64 * LQT];
                 u16 Bs[128 * LPT]; u16 As[32 * LPT]; } ck;   // 49152 B
        struct { u16 Ws[128 * LWT]; u16 Hs[32 * LWT]; } fin;  // 43520 B
    } sm;
    __shared__ float redS[128], redQ[128];
    __shared__ float2 MV[32];
    __shared__ float2 cfs[32];
    int rt = blockIdx.x, b = blockIdx.y;
    int R0 = rt * 32;
    int t = threadIdx.x;
    int lane = t & 63, w = t >> 6, q = lane >> 4, r16 = lane & 15;
    int i2 = w >> 2, j2 = w & 3;      // MFMA1 wave tile (16x16)
    int wr = i2 * 16;                 // MFMA2 wave row base
    int wc = j2 * 32;                 // MFMA2 wave col base

    // ---- fused coef from partials ----
    if (t < 32) {
        const float* p = part + ((size_t)((b * 64 + rt) * 4)) * 96;
        float es = 0.f, lr = 0.f, la = 0.f;
#pragma unroll
        for (int cs = 0; cs < 4; ++cs) {
            es += p[cs * 96 + t];
            lr += p[cs * 96 + 32 + t];
            la += p[cs * 96 + 64 + t];
        }
        float rn = clamp01(rel[b * NN + R0 + t]);
        float inv = 1.f / es;                     // es > 0 (diag edge kept)
        float fsum = rn * (0.6f * lr * inv + 0.4f * la);
        float nrm = 1.f / (fsum + 1e-8f);
        cfs[t] = make_float2(0.6f * inv * rn * nrm, 0.4f * rn * nrm);
    }

    const u16* Qg = Qb + ((size_t)b * NN + R0) * DD;
    {   // stage Q once: 512 slots of 16B
        int row = t >> 4, seg = t & 15;
        *(uint4*)&sm.ck.Qs[row * LQT + seg * 8] = *(const uint4*)&Qg[row * DD + seg * 8];
    }

    const u16* Kg = Kb + (size_t)b * NN * DD;
    const u16* Bg = HnT + (size_t)b * DD * NN;
    int krow0 = t >> 4, krow1 = 32 + (t >> 4), kseg = (t & 15) * 8;
    int bd0 = t >> 3, bd1 = 64 + (t >> 3), bsg = (t & 7) * 8;

    f32x4 acc[2];
    acc[0] = (f32x4){0.f, 0.f, 0.f, 0.f};
    acc[1] = (f32x4){0.f, 0.f, 0.f, 0.f};

    // prologue prefetch (chunk 0)
    uint4 pk0 = *(const uint4*)&Kg[(size_t)krow0 * DD + kseg];
    uint4 pk1 = *(const uint4*)&Kg[(size_t)krow1 * DD + kseg];
    uint4 pb0 = *(const uint4*)&Bg[(size_t)bd0 * NN + bsg];
    uint4 pb1 = *(const uint4*)&Bg[(size_t)bd1 * NN + bsg];

    for (int kc = 0; kc < NN; kc += 64) {
        __syncthreads();            // prev chunk's MFMA reads done
        *(uint4*)&sm.ck.Ks[krow0 * LQT + kseg] = pk0;
        *(uint4*)&sm.ck.Ks[krow1 * LQT + kseg] = pk1;
        *(uint4*)&sm.ck.Bs[bd0 * LPT + bsg] = pb0;
        *(uint4*)&sm.ck.Bs[bd1 * LPT + bsg] = pb1;
        if (kc + 64 < NN) {         // prefetch next chunk (hidden under MFMA)
            int kn = kc + 64;
            pk0 = *(const uint4*)&Kg[(size_t)(kn + krow0) * DD + kseg];
            pk1 = *(const uint4*)&Kg[(size_t)(kn + krow1) * DD + kseg];
            pb0 = *(const uint4*)&Bg[(size_t)bd0 * NN + kn + bsg];
            pb1 = *(const uint4*)&Bg[(size_t)bd1 * NN + kn + bsg];
        }
        __syncthreads();
        // ---- MFMA1: S chunk (same fragment order as stats -> identical S)
        f32x4 sa = (f32x4){0.f, 0.f, 0.f, 0.f};
#pragma unroll
        for (int ksp = 0; ksp < 4; ++ksp) {
            int ko = ksp * 32 + q * 8;
            bf16x8 a0 = *(const bf16x8*)&sm.ck.Qs[(wr + r16) * LQT + ko];
            bf16x8 b0 = *(const bf16x8*)&sm.ck.Ks[(j2 * 16 + r16) * LQT + ko];
            sa = __builtin_amdgcn_mfma_f32_16x16x32_bf16(a0, b0, sa, 0, 0, 0);
        }
        // ---- epilogue: e, A_fuse value, global store + bf16 to As
        int mloc = j2 * 16 + r16;
        int mb = kc + mloc;
        float rm = clamp01(rel[b * NN + mb]);
#pragma unroll
        for (int r = 0; r < 4; ++r) {
            int nl = wr + q * 4 + r;
            int n = R0 + nl;
            float lg = h2f(lgh[(size_t)n * NN + mb]);
            float av = bf2f(am[(size_t)n * NN + mb]);
            float2 cf = cfs[nl];
            float e = __expf(sa[r] + lg);             // masked: -inf -> 0
            float v = rm * fmaf(e, cf.x, av * cf.y);
            Af[((size_t)b * NN + n) * NN + mb] = v;
            sm.ck.As[nl * LPT + mloc] = f2bf(v);
        }
        __syncthreads();
        // ---- MFMA2: H += As @ Bs
#pragma unroll
        for (int kst = 0; kst < 2; ++kst) {
            int ko = kst * 32 + q * 8;
            bf16x8 a0 = *(const bf16x8*)&sm.ck.As[(wr + r16) * LPT + ko];
            bf16x8 b0 = *(const bf16x8*)&sm.ck.Bs[(wc + r16) * LPT + ko];
            bf16x8 b1v = *(const bf16x8*)&sm.ck.Bs[(wc + 16 + r16) * LPT + ko];
            acc[0] = __builtin_amdgcn_mfma_f32_16x16x32_bf16(a0, b0, acc[0], 0, 0, 0);
            acc[1] = __builtin_amdgcn_mfma_f32_16x16x32_bf16(a0, b1v, acc[1], 0, 0, 0);
        }
    }

    // ---- fused final: H -> bf16 LDS, @W_lin, relu, LN1, LN2 ----
    __syncthreads();                // all MFMA reads done before union reuse
#pragma unroll
    for (int rep = 0; rep < 4; ++rep) {
        int e = rep * 512 + t;      // 2048 uint4 slots
        int dp = e >> 4, seg = e & 15;
        *(uint4*)&sm.fin.Ws[dp * LWT + seg * 8] = *(const uint4*)&WlT[dp * DD + seg * 8];
    }
#pragma unroll
    for (int j = 0; j < 2; ++j)
#pragma unroll
        for (int r = 0; r < 4; ++r)
            sm.fin.Hs[(wr + q * 4 + r) * LWT + wc + j * 16 + r16] = f2bf(acc[j][r]);
    __syncthreads();

    f32x4 c2[2];
    c2[0] = (f32x4){0.f, 0.f, 0.f, 0.f};
    c2[1] = (f32x4){0.f, 0.f, 0.f, 0.f};
#pragma unroll
    for (int ksp = 0; ksp < 4; ++ksp) {
        int ko = ksp * 32 + q * 8;
        bf16x8 a0 = *(const bf16x8*)&sm.fin.Hs[(wr + r16) * LWT + ko];
        bf16x8 b0 = *(const bf16x8*)&sm.fin.Ws[(wc + r16) * LWT + ko];
        bf16x8 b1v = *(const bf16x8*)&sm.fin.Ws[(wc + 16 + r16) * LWT + ko];
        c2[0] = __builtin_amdgcn_mfma_f32_16x16x32_bf16(a0, b0, c2[0], 0, 0, 0);
        c2[1] = __builtin_amdgcn_mfma_f32_16x16x32_bf16(a0, b1v, c2[1], 0, 0, 0);
    }
    float v[2][4];
#pragma unroll
    for (int j = 0; j < 2; ++j)
#pragma unroll
        for (int r = 0; r < 4; ++r)
            v[j][r] = fmaxf(c2[j][r], 0.f);

    int c0 = wc + r16, c1 = wc + 16 + r16;
    float s1c0 = s1[c0], s1c1 = s1[c1], b1c0 = b1[c0], b1c1 = b1[c1];
    float s2c0 = s2[c0], s2c1 = s2[c1], b2c0 = b2[c0], b2c1 = b2[c1];
    int g4 = (w & 3) * 32;          // reduction group offset

#pragma unroll
    for (int r = 0; r < 4; ++r) {
        float s = v[0][r] + v[1][r];
        float qq = v[0][r] * v[0][r] + v[1][r] * v[1][r];
#pragma unroll
        for (int off = 1; off < 16; off <<= 1) {
            s += __shfl_xor(s, off);
            qq += __shfl_xor(qq, off);
        }
        if (r16 == 0) {
            int row = wr + q * 4 + r;
            redS[g4 + row] = s;
            redQ[g4 + row] = qq;
        }
    }
    __syncthreads();
    if (t < 32) {
        float s = redS[t] + redS[32 + t] + redS[64 + t] + redS[96 + t];
        float qq = redQ[t] + redQ[32 + t] + redQ[64 + t] + redQ[96 + t];
        float mu = s * (1.f / 128.f);
        float var = qq * (1.f / 128.f) - mu * mu;
        MV[t] = make_float2(mu, 1.f / sqrtf(var + 1e-5f));
    }
    __syncthreads();
    float y[2][4];
#pragma unroll
    for (int r = 0; r < 4; ++r) {
        float2 mv = MV[wr + q * 4 + r];
        y[0][r] = (v[0][r] - mv.x) * mv.y * s1c0 + b1c0;
        y[1][r] = (v[1][r] - mv.x) * mv.y * s1c1 + b1c1;
    }
    __syncthreads();
#pragma unroll
    for (int r = 0; r < 4; ++r) {
        float s = y[0][r] + y[1][r];
        float qq = y[0][r] * y[0][r] + y[1][r] * y[1][r];
#pragma unroll
        for (int off = 1; off < 16; off <<= 1) {
            s += __shfl_xor(s, off);
            qq += __shfl_xor(qq, off);
        }
        if (r16 == 0) {
            int row = wr + q * 4 + r;
            redS[g4 + row] = s;
            redQ[g4 + row] = qq;
        }
    }
    __syncthreads();
    if (t < 32) {
        float s = redS[t] + redS[32 + t] + redS[64 + t] + redS[96 + t];
        float qq = redQ[t] + redQ[32 + t] + redQ[64 + t] + redQ[96 + t];
        float mu = s * (1.f / 128.f);
        float var = qq * (1.f / 128.f) - mu * mu;
        MV[t] = make_float2(mu, 1.f / sqrtf(var + 1e-5f));
    }
    __syncthreads();
#pragma unroll
    for (int r = 0; r < 4; ++r) {
        float2 mv = MV[wr + q * 4 + r];
        size_t o = ((size_t)b * NN + R0 + wr + q * 4 + r) * DD;
        out[o + c0] = (y[0][r] - mv.x) * mv.y * s2c0 + b2c0;
        out[o + c1] = (y[1][r] - mv.x) * mv.y * s2c1 + b2c1;
    }
}

extern "C" void kernel_launch(void* const* d_in, const int* in_sizes, int n_in,
                              void* d_out, int out_size, void* d_ws, size_t ws_size,
                              hipStream_t stream) {
    const float* X = (const float*)d_in[0];
    const float* Msk = (const float*)d_in[1];
    const float* Astat = (const float*)d_in[2];
    const int* Mm = (const int*)d_in[3];
    const float* rel = (const float*)d_in[4];
    const float* Wproj = (const float*)d_in[5];
    const float* Wq = (const float*)d_in[6];
    const float* Wk = (const float*)d_in[7];
    const float* Wlin = (const float*)d_in[8];
    const float* s1 = (const float*)d_in[9];
    const float* b1 = (const float*)d_in[10];
    const float* s2 = (const float*)d_in[11];
    const float* b2 = (const float*)d_in[12];

    float* outMain = (float*)d_out;                       // (B,N,D)
    float* Afuse = outMain + (size_t)BB * NN * DD;        // (B,N,N)

    float* w_ = (float*)d_ws;
    float* Wpq = w_;                                      // 4096 f
    float* Wpk = w_ + 4096;                               // 4096 f
    u16* WlT = (u16*)(w_ + 8192);                         // 16384 u16
    u16* Qb = (u16*)(w_ + 16384);                         // 2097152 u16
    u16* Kb = (u16*)(w_ + 1064960);                       // 2097152 u16
    u16* HnT = (u16*)(w_ + 2113536);                      // 2097152 u16
    u16* lgh = (u16*)(w_ + 3162112);                      // 4194304 u16 (f16)
    u16* am = (u16*)(w_ + 5259264);                       // 4194304 u16 (bf16)
    float* part = w_ + 7356416;                           // 196608 f

    prep_kernel<<<dim3(4192), dim3(256), 0, stream>>>(
        Astat, Mm, Wproj, Wq, Wk, Wlin, lgh, am, Wpq, Wpk, WlT);
    proj3_kernel<<<dim3(512), dim3(256), 0, stream>>>(X, Msk, Wproj, Wpq, Wpk, HnT, Qb, Kb);

    stats_kernel<<<dim3(4, 64, 8), dim3(256), 0, stream>>>(
        Qb, Kb, lgh, am, rel, part);
    prop_kernel<<<dim3(64, 8), dim3(512), 0, stream>>>(
        Qb, Kb, lgh, am, part, rel, HnT, WlT, s1, b1, s2, b2, Afuse, outMain);
}

// Round 7
// 369.403 us; speedup vs baseline: 1.1022x; 1.1022x over previous
//
#include <hip/hip_runtime.h>
#include <math.h>

#define BB 8
#define NN 2048
#define SS 16
#define CC 32
#define DD 128

typedef unsigned short u16;
typedef __attribute__((ext_vector_type(8))) short bf16x8;
typedef __attribute__((ext_vector_type(4))) float f32x4;

__device__ inline u16 f2bf(float f) {
    union { float f; unsigned u; } c; c.f = f;
    unsigned r = c.u + 0x7fff + ((c.u >> 16) & 1);   // round-to-nearest-even
    return (u16)(r >> 16);
}
__device__ inline float bf2f(u16 h) {
    union { unsigned u; float f; } c; c.u = ((unsigned)h) << 16;
    return c.f;
}
__device__ inline u16 f2h(float f) {
    union { _Float16 h; u16 u; } c; c.h = (_Float16)f;
    return c.u;
}
__device__ inline float h2f(u16 u) {
    union { _Float16 h; u16 v; } c; c.v = u;
    return (float)c.h;
}
__device__ inline float clamp01(float v) { return fminf(fmaxf(v, 0.f), 1.f); }

// ---------------- K1: merged prep: bias tables + wcomb + wlt ---------------
__global__ __launch_bounds__(256) void prep_kernel(const float* __restrict__ Astat,
                                                   const int* __restrict__ Mm,
                                                   const float* __restrict__ Wproj,
                                                   const float* __restrict__ Wq,
                                                   const float* __restrict__ Wk,
                                                   const float* __restrict__ Wl,
                                                   u16* __restrict__ lgh,
                                                   u16* __restrict__ am,
                                                   float* __restrict__ Wpq,
                                                   float* __restrict__ Wpk,
                                                   u16* __restrict__ WlT) {
    int bx = blockIdx.x;
    if (bx < 4096) {
        size_t g = ((size_t)bx * 256 + threadIdx.x) * 4;   // 4194304 total
        float4 a4 = *(const float4*)&Astat[g];
        int4 m4 = *(const int4*)&Mm[g];
        float a[4] = {a4.x, a4.y, a4.z, a4.w};
        int mm[4] = {m4.x, m4.y, m4.z, m4.w};
        ushort4 lo, ao;
        u16 lg[4], ab[4];
#pragma unroll
        for (int j = 0; j < 4; ++j) {
            float p = fminf(fmaxf(a[j], 1e-3f), 1.f - 1e-3f);
            float l = __logf(p / (1.f - p));          // ETA = 1.0
            lg[j] = mm[j] ? f2h(l) : (u16)0xFC00;     // -inf f16 when masked
            ab[j] = mm[j] ? f2bf(a[j]) : (u16)0;
        }
        lo.x = lg[0]; lo.y = lg[1]; lo.z = lg[2]; lo.w = lg[3];
        ao.x = ab[0]; ao.y = ab[1]; ao.z = ab[2]; ao.w = ab[3];
        *(ushort4*)&lgh[g] = lo;
        *(ushort4*)&am[g] = ao;
    } else if (bx < 4128) {
        int i = (bx - 4096) * 256 + threadIdx.x;      // 8192 outputs
        int d = i & 127;
        int c = (i >> 7) & 31;
        int mat = i >> 12;
        const float* Wt = mat ? Wk : Wq;
        float acc = 0.f;
#pragma unroll 4
        for (int e = 0; e < DD; ++e)
            acc = fmaf(Wproj[c * DD + e], Wt[e * DD + d], acc);
        (mat ? Wpk : Wpq)[c * DD + d] = acc;
    } else {
        int i = (bx - 4128) * 256 + threadIdx.x;      // 16384 outputs
        int dp = i >> 7, d = i & 127;
        WlT[dp * DD + d] = f2bf(Wl[d * DD + dp]);
    }
}

// ---------------- K3: fused pool + Hn/Q/K projections, emitted bf16 --------
__global__ __launch_bounds__(256) void proj3_kernel(const float* __restrict__ X,
                                                    const float* __restrict__ Msk,
                                                    const float* __restrict__ Wproj,
                                                    const float* __restrict__ Wpq,
                                                    const float* __restrict__ Wpk,
                                                    u16* __restrict__ HnT,
                                                    u16* __restrict__ Qb,
                                                    u16* __restrict__ Kb) {
    __shared__ float wp[CC * DD], wq[CC * DD], wk[CC * DD];
    __shared__ float xs[CC * 36];
    int t = threadIdx.x;
    for (int i = t; i < CC * DD; i += 256) {
        wp[i] = Wproj[i];
        wq[i] = Wpq[i];
        wk[i] = Wpk[i];
    }
    int rbase = blockIdx.x * 32;
    {   // masked temporal mean pooling: thread = (row, 4-col group)
        int row = t >> 3, cg = t & 7;
        const float* xrow = X + ((size_t)(rbase + row) * SS) * CC + cg * 4;
        const float* mrow = Msk + (size_t)(rbase + row) * SS;
        float4 acc = make_float4(0.f, 0.f, 0.f, 0.f);
        float msum = 0.f;
#pragma unroll
        for (int s = 0; s < SS; ++s) {
            float mv = mrow[s];
            float4 xv = *(const float4*)&xrow[s * CC];
            msum += mv;
            acc.x = fmaf(xv.x, mv, acc.x);
            acc.y = fmaf(xv.y, mv, acc.y);
            acc.z = fmaf(xv.z, mv, acc.z);
            acc.w = fmaf(xv.w, mv, acc.w);
        }
        float inv = 1.f / fmaxf(msum, 1.0f);
        xs[(cg * 4 + 0) * 36 + row] = acc.x * inv;
        xs[(cg * 4 + 1) * 36 + row] = acc.y * inv;
        xs[(cg * 4 + 2) * 36 + row] = acc.z * inv;
        xs[(cg * 4 + 3) * 36 + row] = acc.w * inv;
    }
    __syncthreads();

    int col = t & 127;
    int g = t >> 7;
    float ah[16], aq[16], ak[16];
#pragma unroll
    for (int i = 0; i < 16; ++i) { ah[i] = 0.f; aq[i] = 0.f; ak[i] = 0.f; }

#pragma unroll 4
    for (int k = 0; k < CC; ++k) {
        float wpv = wp[k * DD + col], wqv = wq[k * DD + col], wkv = wk[k * DD + col];
        const float4* xp = (const float4*)&xs[k * 36 + g * 16];
        float4 a0 = xp[0], a1 = xp[1], a2 = xp[2], a3 = xp[3];
        float xv[16] = {a0.x, a0.y, a0.z, a0.w, a1.x, a1.y, a1.z, a1.w,
                        a2.x, a2.y, a2.z, a2.w, a3.x, a3.y, a3.z, a3.w};
#pragma unroll
        for (int i = 0; i < 16; ++i) {
            ah[i] = fmaf(xv[i], wpv, ah[i]);
            aq[i] = fmaf(xv[i], wqv, aq[i]);
            ak[i] = fmaf(xv[i], wkv, ak[i]);
        }
    }
    const float scale = 0.08838834764831845f;     // 1/sqrt(128) folded into Q
#pragma unroll
    for (int i = 0; i < 16; ++i) {
        size_t row = (size_t)(rbase + g * 16 + i);
        Qb[row * DD + col] = f2bf(aq[i] * scale);
        Kb[row * DD + col] = f2bf(ak[i]);
    }
    int b = rbase >> 11;
    int n0 = (rbase & (NN - 1)) + g * 16;
    u16* hp = HnT + (size_t)b * DD * NN + (size_t)col * NN + n0;
    unsigned pk[8];
#pragma unroll
    for (int i = 0; i < 8; ++i)
        pk[i] = (unsigned)f2bf(ah[2 * i]) | ((unsigned)f2bf(ah[2 * i + 1]) << 16);
    *(uint4*)&hp[0] = make_uint4(pk[0], pk[1], pk[2], pk[3]);
    *(uint4*)&hp[8] = make_uint4(pk[4], pk[5], pk[6], pk[7]);
}

// ---------------- K4: stats — QK^T row partials (no e materialization) -----
// grid (cs=4, rt=64, b=8) = 2048 blocks; block: 32 rows x 512 cols (4 tiles).
// Round-1-proven staging (direct global->LDS, no wide register prefetch —
// a uint4[8] prefetch array spilled to scratch: 204MB HBM writes, +30µs).
#define LQT 136
__global__ __launch_bounds__(256) void stats_kernel(
        const u16* __restrict__ Qb, const u16* __restrict__ Kb,
        const u16* __restrict__ lgh, const u16* __restrict__ am,
        const float* __restrict__ rel,
        float* __restrict__ part) {
    __shared__ u16 Qs[32 * LQT];
    __shared__ u16 Ks[128 * LQT];
    __shared__ float redE[128], redR[128], redA[128];
    int cs = blockIdx.x, rt = blockIdx.y, b = blockIdx.z;
    int R0 = rt * 32, C0 = cs * 512;
    int t = threadIdx.x;
    int lane = t & 63, w = t >> 6, q = lane >> 4, r16 = lane & 15;

    const u16* Qg = Qb + ((size_t)b * NN + R0) * DD;
#pragma unroll
    for (int rep = 0; rep < 2; ++rep) {
        int e = rep * 256 + t;
        int row = e >> 4, seg = e & 15;
        *(uint4*)&Qs[row * LQT + seg * 8] = *(const uint4*)&Qg[row * DD + seg * 8];
    }
    const u16* Kg = Kb + (size_t)b * NN * DD;
    float ER[2][4], LR[2][4], LA[2][4];
#pragma unroll
    for (int i = 0; i < 2; ++i)
#pragma unroll
        for (int r = 0; r < 4; ++r) { ER[i][r] = 0.f; LR[i][r] = 0.f; LA[i][r] = 0.f; }

    for (int ct = 0; ct < 4; ++ct) {
        __syncthreads();
#pragma unroll
        for (int rep = 0; rep < 8; ++rep) {       // K tile: 128 cols x 128 k
            int e = rep * 256 + t;
            int colr = e >> 4, seg = e & 15;
            *(uint4*)&Ks[colr * LQT + seg * 8] =
                *(const uint4*)&Kg[(size_t)(C0 + ct * 128 + colr) * DD + seg * 8];
        }
        __syncthreads();
        f32x4 acc[2][2];
#pragma unroll
        for (int i = 0; i < 2; ++i)
#pragma unroll
            for (int j = 0; j < 2; ++j)
                acc[i][j] = (f32x4){0.f, 0.f, 0.f, 0.f};
#pragma unroll
        for (int ksp = 0; ksp < 4; ++ksp) {
            int ko = ksp * 32 + q * 8;
            bf16x8 a0 = *(const bf16x8*)&Qs[r16 * LQT + ko];
            bf16x8 a1 = *(const bf16x8*)&Qs[(16 + r16) * LQT + ko];
            bf16x8 b0 = *(const bf16x8*)&Ks[(w * 32 + r16) * LQT + ko];
            bf16x8 b1 = *(const bf16x8*)&Ks[(w * 32 + 16 + r16) * LQT + ko];
            acc[0][0] = __builtin_amdgcn_mfma_f32_16x16x32_bf16(a0, b0, acc[0][0], 0, 0, 0);
            acc[0][1] = __builtin_amdgcn_mfma_f32_16x16x32_bf16(a0, b1, acc[0][1], 0, 0, 0);
            acc[1][0] = __builtin_amdgcn_mfma_f32_16x16x32_bf16(a1, b0, acc[1][0], 0, 0, 0);
            acc[1][1] = __builtin_amdgcn_mfma_f32_16x16x32_bf16(a1, b1, acc[1][1], 0, 0, 0);
        }
        int m0 = C0 + ct * 128 + w * 32;
        float rm0 = clamp01(rel[b * NN + m0 + r16]);
        float rm1 = clamp01(rel[b * NN + m0 + 16 + r16]);
#pragma unroll
        for (int i = 0; i < 2; ++i)
#pragma unroll
            for (int r = 0; r < 4; ++r) {
                int n = R0 + i * 16 + q * 4 + r;
                const u16* lrow = lgh + (size_t)n * NN + m0;
                const u16* arow = am + (size_t)n * NN + m0;
                float lg0 = h2f(lrow[r16]), lg1 = h2f(lrow[16 + r16]);
                float a0 = bf2f(arow[r16]), a1 = bf2f(arow[16 + r16]);
                float e0 = __expf(acc[i][0][r] + lg0);        // masked: -inf -> 0
                float e1 = __expf(acc[i][1][r] + lg1);
                ER[i][r] += e0 + e1;
                LR[i][r] = fmaf(e0, rm0, fmaf(e1, rm1, LR[i][r]));
                LA[i][r] = fmaf(a0, rm0, fmaf(a1, rm1, LA[i][r]));
            }
    }
#pragma unroll
    for (int i = 0; i < 2; ++i)
#pragma unroll
        for (int r = 0; r < 4; ++r) {
            float e = ER[i][r], lr = LR[i][r], la = LA[i][r];
#pragma unroll
            for (int off = 1; off < 16; off <<= 1) {
                e += __shfl_xor(e, off);
                lr += __shfl_xor(lr, off);
                la += __shfl_xor(la, off);
            }
            if (r16 == 0) {
                int row = i * 16 + q * 4 + r;
                redE[w * 32 + row] = e;
                redR[w * 32 + row] = lr;
                redA[w * 32 + row] = la;
            }
        }
    __syncthreads();
    if (t < 32) {
        float es = redE[t] + redE[32 + t] + redE[64 + t] + redE[96 + t];
        float lr = redR[t] + redR[32 + t] + redR[64 + t] + redR[96 + t];
        float la = redA[t] + redA[32 + t] + redA[64 + t] + redA[96 + t];
        float* p = part + ((size_t)((b * 64 + rt) * 4 + cs)) * 96;
        p[t] = es;
        p[32 + t] = lr;
        p[64 + t] = la;
    }
}

// ---------------- K5: recompute-e GEMM1 + A_fuse + coef + W_lin/LN tail ----
#define LPT 72
#define LWT 136
__global__ __launch_bounds__(512) void prop_kernel(
        const u16* __restrict__ Qb, const u16* __restrict__ Kb,
        const u16* __restrict__ lgh, const u16* __restrict__ am,
        const float* __restrict__ part, const float* __restrict__ rel,
        const u16* __restrict__ HnT, const u16* __restrict__ WlT,
        const float* __restrict__ s1, const float* __restrict__ b1,
        const float* __restrict__ s2, const float* __restrict__ b2,
        float* __restrict__ Af, float* __restrict__ out) {
    __shared__ union {
        struct { u16 Qs[32 * LQT]; u16 Ks[64 * LQT];
                 u16 Bs[128 * LPT]; u16 As[32 * LPT]; } ck;   // 49152 B
        struct { u16 Ws[128 * LWT]; u16 Hs[32 * LWT]; } fin;  // 43520 B
    } sm;
    __shared__ float redS[128], redQ[128];
    __shared__ float2 MV[32];
    __shared__ float2 cfs[32];
    int rt = blockIdx.x, b = blockIdx.y;
    int R0 = rt * 32;
    int t = threadIdx.x;
    int lane = t & 63, w = t >> 6, q = lane >> 4, r16 = lane & 15;
    int i2 = w >> 2, j2 = w & 3;      // MFMA1 wave tile (16x16)
    int wr = i2 * 16;                 // MFMA2 wave row base
    int wc = j2 * 32;                 // MFMA2 wave col base

    // ---- fused coef from partials ----
    if (t < 32) {
        const float* p = part + ((size_t)((b * 64 + rt) * 4)) * 96;
        float es = 0.f, lr = 0.f, la = 0.f;
#pragma unroll
        for (int cs = 0; cs < 4; ++cs) {
            es += p[cs * 96 + t];
            lr += p[cs * 96 + 32 + t];
            la += p[cs * 96 + 64 + t];
        }
        float rn = clamp01(rel[b * NN + R0 + t]);
        float inv = 1.f / es;                     // es > 0 (diag edge kept)
        float fsum = rn * (0.6f * lr * inv + 0.4f * la);
        float nrm = 1.f / (fsum + 1e-8f);
        cfs[t] = make_float2(0.6f * inv * rn * nrm, 0.4f * rn * nrm);
    }

    const u16* Qg = Qb + ((size_t)b * NN + R0) * DD;
    {   // stage Q once: 512 slots of 16B
        int row = t >> 4, seg = t & 15;
        *(uint4*)&sm.ck.Qs[row * LQT + seg * 8] = *(const uint4*)&Qg[row * DD + seg * 8];
    }

    const u16* Kg = Kb + (size_t)b * NN * DD;
    const u16* Bg = HnT + (size_t)b * DD * NN;
    int krow0 = t >> 4, krow1 = 32 + (t >> 4), kseg = (t & 15) * 8;
    int bd0 = t >> 3, bd1 = 64 + (t >> 3), bsg = (t & 7) * 8;

    f32x4 acc[2];
    acc[0] = (f32x4){0.f, 0.f, 0.f, 0.f};
    acc[1] = (f32x4){0.f, 0.f, 0.f, 0.f};

    // prologue prefetch (chunk 0)
    uint4 pk0 = *(const uint4*)&Kg[(size_t)krow0 * DD + kseg];
    uint4 pk1 = *(const uint4*)&Kg[(size_t)krow1 * DD + kseg];
    uint4 pb0 = *(const uint4*)&Bg[(size_t)bd0 * NN + bsg];
    uint4 pb1 = *(const uint4*)&Bg[(size_t)bd1 * NN + bsg];

    for (int kc = 0; kc < NN; kc += 64) {
        __syncthreads();            // prev chunk's MFMA reads done
        *(uint4*)&sm.ck.Ks[krow0 * LQT + kseg] = pk0;
        *(uint4*)&sm.ck.Ks[krow1 * LQT + kseg] = pk1;
        *(uint4*)&sm.ck.Bs[bd0 * LPT + bsg] = pb0;
        *(uint4*)&sm.ck.Bs[bd1 * LPT + bsg] = pb1;
        if (kc + 64 < NN) {         // prefetch next chunk (hidden under MFMA)
            int kn = kc + 64;
            pk0 = *(const uint4*)&Kg[(size_t)(kn + krow0) * DD + kseg];
            pk1 = *(const uint4*)&Kg[(size_t)(kn + krow1) * DD + kseg];
            pb0 = *(const uint4*)&Bg[(size_t)bd0 * NN + kn + bsg];
            pb1 = *(const uint4*)&Bg[(size_t)bd1 * NN + kn + bsg];
        }
        __syncthreads();
        // ---- MFMA1: S chunk (same fragment order as stats -> identical S)
        f32x4 sa = (f32x4){0.f, 0.f, 0.f, 0.f};
#pragma unroll
        for (int ksp = 0; ksp < 4; ++ksp) {
            int ko = ksp * 32 + q * 8;
            bf16x8 a0 = *(const bf16x8*)&sm.ck.Qs[(wr + r16) * LQT + ko];
            bf16x8 b0 = *(const bf16x8*)&sm.ck.Ks[(j2 * 16 + r16) * LQT + ko];
            sa = __builtin_amdgcn_mfma_f32_16x16x32_bf16(a0, b0, sa, 0, 0, 0);
        }
        // ---- epilogue: e, A_fuse value, global store + bf16 to As
        int mloc = j2 * 16 + r16;
        int mb = kc + mloc;
        float rm = clamp01(rel[b * NN + mb]);
#pragma unroll
        for (int r = 0; r < 4; ++r) {
            int nl = wr + q * 4 + r;
            int n = R0 + nl;
            float lg = h2f(lgh[(size_t)n * NN + mb]);
            float av = bf2f(am[(size_t)n * NN + mb]);
            float2 cf = cfs[nl];
            float e = __expf(sa[r] + lg);             // masked: -inf -> 0
            float v = rm * fmaf(e, cf.x, av * cf.y);
            Af[((size_t)b * NN + n) * NN + mb] = v;
            sm.ck.As[nl * LPT + mloc] = f2bf(v);
        }
        __syncthreads();
        // ---- MFMA2: H += As @ Bs
#pragma unroll
        for (int kst = 0; kst < 2; ++kst) {
            int ko = kst * 32 + q * 8;
            bf16x8 a0 = *(const bf16x8*)&sm.ck.As[(wr + r16) * LPT + ko];
            bf16x8 b0 = *(const bf16x8*)&sm.ck.Bs[(wc + r16) * LPT + ko];
            bf16x8 b1v = *(const bf16x8*)&sm.ck.Bs[(wc + 16 + r16) * LPT + ko];
            acc[0] = __builtin_amdgcn_mfma_f32_16x16x32_bf16(a0, b0, acc[0], 0, 0, 0);
            acc[1] = __builtin_amdgcn_mfma_f32_16x16x32_bf16(a0, b1v, acc[1], 0, 0, 0);
        }
    }

    // ---- fused final: H -> bf16 LDS, @W_lin, relu, LN1, LN2 ----
    __syncthreads();                // all MFMA reads done before union reuse
#pragma unroll
    for (int rep = 0; rep < 4; ++rep) {
        int e = rep * 512 + t;      // 2048 uint4 slots
        int dp = e >> 4, seg = e & 15;
        *(uint4*)&sm.fin.Ws[dp * LWT + seg * 8] = *(const uint4*)&WlT[dp * DD + seg * 8];
    }
#pragma unroll
    for (int j = 0; j < 2; ++j)
#pragma unroll
        for (int r = 0; r < 4; ++r)
            sm.fin.Hs[(wr + q * 4 + r) * LWT + wc + j * 16 + r16] = f2bf(acc[j][r]);
    __syncthreads();

    f32x4 c2[2];
    c2[0] = (f32x4){0.f, 0.f, 0.f, 0.f};
    c2[1] = (f32x4){0.f, 0.f, 0.f, 0.f};
#pragma unroll
    for (int ksp = 0; ksp < 4; ++ksp) {
        int ko = ksp * 32 + q * 8;
        bf16x8 a0 = *(const bf16x8*)&sm.fin.Hs[(wr + r16) * LWT + ko];
        bf16x8 b0 = *(const bf16x8*)&sm.fin.Ws[(wc + r16) * LWT + ko];
        bf16x8 b1v = *(const bf16x8*)&sm.fin.Ws[(wc + 16 + r16) * LWT + ko];
        c2[0] = __builtin_amdgcn_mfma_f32_16x16x32_bf16(a0, b0, c2[0], 0, 0, 0);
        c2[1] = __builtin_amdgcn_mfma_f32_16x16x32_bf16(a0, b1v, c2[1], 0, 0, 0);
    }
    float v[2][4];
#pragma unroll
    for (int j = 0; j < 2; ++j)
#pragma unroll
        for (int r = 0; r < 4; ++r)
            v[j][r] = fmaxf(c2[j][r], 0.f);

    int c0 = wc + r16, c1 = wc + 16 + r16;
    float s1c0 = s1[c0], s1c1 = s1[c1], b1c0 = b1[c0], b1c1 = b1[c1];
    float s2c0 = s2[c0], s2c1 = s2[c1], b2c0 = b2[c0], b2c1 = b2[c1];
    int g4 = (w & 3) * 32;          // reduction group offset

#pragma unroll
    for (int r = 0; r < 4; ++r) {
        float s = v[0][r] + v[1][r];
        float qq = v[0][r] * v[0][r] + v[1][r] * v[1][r];
#pragma unroll
        for (int off = 1; off < 16; off <<= 1) {
            s += __shfl_xor(s, off);
            qq += __shfl_xor(qq, off);
        }
        if (r16 == 0) {
            int row = wr + q * 4 + r;
            redS[g4 + row] = s;
            redQ[g4 + row] = qq;
        }
    }
    __syncthreads();
    if (t < 32) {
        float s = redS[t] + redS[32 + t] + redS[64 + t] + redS[96 + t];
        float qq = redQ[t] + redQ[32 + t] + redQ[64 + t] + redQ[96 + t];
        float mu = s * (1.f / 128.f);
        float var = qq * (1.f / 128.f) - mu * mu;
        MV[t] = make_float2(mu, 1.f / sqrtf(var + 1e-5f));
    }
    __syncthreads();
    float y[2][4];
#pragma unroll
    for (int r = 0; r < 4; ++r) {
        float2 mv = MV[wr + q * 4 + r];
        y[0][r] = (v[0][r] - mv.x) * mv.y * s1c0 + b1c0;
        y[1][r] = (v[1][r] - mv.x) * mv.y * s1c1 + b1c1;
    }
    __syncthreads();
#pragma unroll
    for (int r = 0; r < 4; ++r) {
        float s = y[0][r] + y[1][r];
        float qq = y[0][r] * y[0][r] + y[1][r] * y[1][r];
#pragma unroll
        for (int off = 1; off < 16; off <<= 1) {
            s += __shfl_xor(s, off);
            qq += __shfl_xor(qq, off);
        }
        if (r16 == 0) {
            int row = wr + q * 4 + r;
            redS[g4 + row] = s;
            redQ[g4 + row] = qq;
        }
    }
    __syncthreads();
    if (t < 32) {
        float s = redS[t] + redS[32 + t] + redS[64 + t] + redS[96 + t];
        float qq = redQ[t] + redQ[32 + t] + redQ[64 + t] + redQ[96 + t];
        float mu = s * (1.f / 128.f);
        float var = qq * (1.f / 128.f) - mu * mu;
        MV[t] = make_float2(mu, 1.f / sqrtf(var + 1e-5f));
    }
    __syncthreads();
#pragma unroll
    for (int r = 0; r < 4; ++r) {
        float2 mv = MV[wr + q * 4 + r];
        size_t o = ((size_t)b * NN + R0 + wr + q * 4 + r) * DD;
        out[o + c0] = (y[0][r] - mv.x) * mv.y * s2c0 + b2c0;
        out[o + c1] = (y[1][r] - mv.x) * mv.y * s2c1 + b2c1;
    }
}

extern "C" void kernel_launch(void* const* d_in, const int* in_sizes, int n_in,
                              void* d_out, int out_size, void* d_ws, size_t ws_size,
                              hipStream_t stream) {
    const float* X = (const float*)d_in[0];
    const float* Msk = (const float*)d_in[1];
    const float* Astat = (const float*)d_in[2];
    const int* Mm = (const int*)d_in[3];
    const float* rel = (const float*)d_in[4];
    const float* Wproj = (const float*)d_in[5];
    const float* Wq = (const float*)d_in[6];
    const float* Wk = (const float*)d_in[7];
    const float* Wlin = (const float*)d_in[8];
    const float* s1 = (const float*)d_in[9];
    const float* b1 = (const float*)d_in[10];
    const float* s2 = (const float*)d_in[11];
    const float* b2 = (const float*)d_in[12];

    float* outMain = (float*)d_out;                       // (B,N,D)
    float* Afuse = outMain + (size_t)BB * NN * DD;        // (B,N,N)

    float* w_ = (float*)d_ws;
    float* Wpq = w_;                                      // 4096 f
    float* Wpk = w_ + 4096;                               // 4096 f
    u16* WlT = (u16*)(w_ + 8192);                         // 16384 u16
    u16* Qb = (u16*)(w_ + 16384);                         // 2097152 u16
    u16* Kb = (u16*)(w_ + 1064960);                       // 2097152 u16
    u16* HnT = (u16*)(w_ + 2113536);                      // 2097152 u16
    u16* lgh = (u16*)(w_ + 3162112);                      // 4194304 u16 (f16)
    u16* am = (u16*)(w_ + 5259264);                       // 4194304 u16 (bf16)
    float* part = w_ + 7356416;                           // 196608 f

    prep_kernel<<<dim3(4192), dim3(256), 0, stream>>>(
        Astat, Mm, Wproj, Wq, Wk, Wlin, lgh, am, Wpq, Wpk, WlT);
    proj3_kernel<<<dim3(512), dim3(256), 0, stream>>>(X, Msk, Wproj, Wpq, Wpk, HnT, Qb, Kb);

    stats_kernel<<<dim3(4, 64, 8), dim3(256), 0, stream>>>(
        Qb, Kb, lgh, am, rel, part);
    prop_kernel<<<dim3(64, 8), dim3(512), 0, stream>>>(
        Qb, Kb, lgh, am, part, rel, HnT, WlT, s1, b1, s2, b2, Afuse, outMain);
}

// Round 8
// 308.754 us; speedup vs baseline: 1.3188x; 1.1964x over previous
//
#include <hip/hip_runtime.h>
#include <math.h>

#define BB 8
#define NN 2048
#define SS 16
#define CC 32
#define DD 128

typedef unsigned short u16;
typedef __attribute__((ext_vector_type(8))) short bf16x8;
typedef __attribute__((ext_vector_type(4))) float f32x4;

__device__ inline u16 f2bf(float f) {
    union { float f; unsigned u; } c; c.f = f;
    unsigned r = c.u + 0x7fff + ((c.u >> 16) & 1);   // round-to-nearest-even
    return (u16)(r >> 16);
}
__device__ inline float bf2f(u16 h) {
    union { unsigned u; float f; } c; c.u = ((unsigned)h) << 16;
    return c.f;
}
__device__ inline u16 f2h(float f) {
    union { _Float16 h; u16 u; } c; c.h = (_Float16)f;
    return c.u;
}
__device__ inline float h2f(u16 u) {
    union { _Float16 h; u16 v; } c; c.v = u;
    return (float)c.h;
}
__device__ inline float clamp01(float v) { return fminf(fmaxf(v, 0.f), 1.f); }

// ---------------- K1: merged prep: bias tables + wcomb + wlt ---------------
__global__ __launch_bounds__(256) void prep_kernel(const float* __restrict__ Astat,
                                                   const int* __restrict__ Mm,
                                                   const float* __restrict__ Wproj,
                                                   const float* __restrict__ Wq,
                                                   const float* __restrict__ Wk,
                                                   const float* __restrict__ Wl,
                                                   u16* __restrict__ lgh,
                                                   u16* __restrict__ am,
                                                   float* __restrict__ Wpq,
                                                   float* __restrict__ Wpk,
                                                   u16* __restrict__ WlT) {
    int bx = blockIdx.x;
    if (bx < 4096) {
        size_t g = ((size_t)bx * 256 + threadIdx.x) * 4;   // 4194304 total
        float4 a4 = *(const float4*)&Astat[g];
        int4 m4 = *(const int4*)&Mm[g];
        float a[4] = {a4.x, a4.y, a4.z, a4.w};
        int mm[4] = {m4.x, m4.y, m4.z, m4.w};
        ushort4 lo, ao;
        u16 lg[4], ab[4];
#pragma unroll
        for (int j = 0; j < 4; ++j) {
            float p = fminf(fmaxf(a[j], 1e-3f), 1.f - 1e-3f);
            float l = __logf(p / (1.f - p));          // ETA = 1.0
            lg[j] = mm[j] ? f2h(l) : (u16)0xFC00;     // -inf f16 when masked
            ab[j] = mm[j] ? f2bf(a[j]) : (u16)0;
        }
        lo.x = lg[0]; lo.y = lg[1]; lo.z = lg[2]; lo.w = lg[3];
        ao.x = ab[0]; ao.y = ab[1]; ao.z = ab[2]; ao.w = ab[3];
        *(ushort4*)&lgh[g] = lo;
        *(ushort4*)&am[g] = ao;
    } else if (bx < 4128) {
        int i = (bx - 4096) * 256 + threadIdx.x;      // 8192 outputs
        int d = i & 127;
        int c = (i >> 7) & 31;
        int mat = i >> 12;
        const float* Wt = mat ? Wk : Wq;
        float acc = 0.f;
#pragma unroll 4
        for (int e = 0; e < DD; ++e)
            acc = fmaf(Wproj[c * DD + e], Wt[e * DD + d], acc);
        (mat ? Wpk : Wpq)[c * DD + d] = acc;
    } else {
        int i = (bx - 4128) * 256 + threadIdx.x;      // 16384 outputs
        int dp = i >> 7, d = i & 127;
        WlT[dp * DD + d] = f2bf(Wl[d * DD + dp]);
    }
}

// ---------------- K3: fused pool + Hn/Q/K projections, emitted bf16 --------
__global__ __launch_bounds__(256) void proj3_kernel(const float* __restrict__ X,
                                                    const float* __restrict__ Msk,
                                                    const float* __restrict__ Wproj,
                                                    const float* __restrict__ Wpq,
                                                    const float* __restrict__ Wpk,
                                                    u16* __restrict__ HnT,
                                                    u16* __restrict__ Qb,
                                                    u16* __restrict__ Kb) {
    __shared__ float wp[CC * DD], wq[CC * DD], wk[CC * DD];
    __shared__ float xs[CC * 36];
    int t = threadIdx.x;
    for (int i = t; i < CC * DD; i += 256) {
        wp[i] = Wproj[i];
        wq[i] = Wpq[i];
        wk[i] = Wpk[i];
    }
    int rbase = blockIdx.x * 32;
    {   // masked temporal mean pooling: thread = (row, 4-col group)
        int row = t >> 3, cg = t & 7;
        const float* xrow = X + ((size_t)(rbase + row) * SS) * CC + cg * 4;
        const float* mrow = Msk + (size_t)(rbase + row) * SS;
        float4 acc = make_float4(0.f, 0.f, 0.f, 0.f);
        float msum = 0.f;
#pragma unroll
        for (int s = 0; s < SS; ++s) {
            float mv = mrow[s];
            float4 xv = *(const float4*)&xrow[s * CC];
            msum += mv;
            acc.x = fmaf(xv.x, mv, acc.x);
            acc.y = fmaf(xv.y, mv, acc.y);
            acc.z = fmaf(xv.z, mv, acc.z);
            acc.w = fmaf(xv.w, mv, acc.w);
        }
        float inv = 1.f / fmaxf(msum, 1.0f);
        xs[(cg * 4 + 0) * 36 + row] = acc.x * inv;
        xs[(cg * 4 + 1) * 36 + row] = acc.y * inv;
        xs[(cg * 4 + 2) * 36 + row] = acc.z * inv;
        xs[(cg * 4 + 3) * 36 + row] = acc.w * inv;
    }
    __syncthreads();

    int col = t & 127;
    int g = t >> 7;
    float ah[16], aq[16], ak[16];
#pragma unroll
    for (int i = 0; i < 16; ++i) { ah[i] = 0.f; aq[i] = 0.f; ak[i] = 0.f; }

#pragma unroll 4
    for (int k = 0; k < CC; ++k) {
        float wpv = wp[k * DD + col], wqv = wq[k * DD + col], wkv = wk[k * DD + col];
        const float4* xp = (const float4*)&xs[k * 36 + g * 16];
        float4 a0 = xp[0], a1 = xp[1], a2 = xp[2], a3 = xp[3];
        float xv[16] = {a0.x, a0.y, a0.z, a0.w, a1.x, a1.y, a1.z, a1.w,
                        a2.x, a2.y, a2.z, a2.w, a3.x, a3.y, a3.z, a3.w};
#pragma unroll
        for (int i = 0; i < 16; ++i) {
            ah[i] = fmaf(xv[i], wpv, ah[i]);
            aq[i] = fmaf(xv[i], wqv, aq[i]);
            ak[i] = fmaf(xv[i], wkv, ak[i]);
        }
    }
    const float scale = 0.08838834764831845f;     // 1/sqrt(128) folded into Q
#pragma unroll
    for (int i = 0; i < 16; ++i) {
        size_t row = (size_t)(rbase + g * 16 + i);
        Qb[row * DD + col] = f2bf(aq[i] * scale);
        Kb[row * DD + col] = f2bf(ak[i]);
    }
    int b = rbase >> 11;
    int n0 = (rbase & (NN - 1)) + g * 16;
    u16* hp = HnT + (size_t)b * DD * NN + (size_t)col * NN + n0;
    unsigned pk[8];
#pragma unroll
    for (int i = 0; i < 8; ++i)
        pk[i] = (unsigned)f2bf(ah[2 * i]) | ((unsigned)f2bf(ah[2 * i + 1]) << 16);
    *(uint4*)&hp[0] = make_uint4(pk[0], pk[1], pk[2], pk[3]);
    *(uint4*)&hp[8] = make_uint4(pk[4], pk[5], pk[6], pk[7]);
}

// ---------------- K5: two-pass fused attention-propagate kernel ------------
// grid (rt=64, b=8), 512 threads (8 waves). Pass 1: iterate 32 K-chunks,
// MFMA1 S = Q@K^T, accumulate per-lane ER/LR/LA (denominator sums) — no
// stores. In-block reduce -> coef. Pass 2: re-iterate chunks, recompute e
// bitwise-identically, materialize A_fuse, MFMA2 H += A@Hn, then fused
// H@W_lin -> relu -> LN1 -> LN2. No stats kernel, no part round-trip.
#define LQT 136
#define LPT 72
#define LWT 136
__global__ __launch_bounds__(512) void prop_kernel(
        const u16* __restrict__ Qb, const u16* __restrict__ Kb,
        const u16* __restrict__ lgh, const u16* __restrict__ am,
        const float* __restrict__ rel,
        const u16* __restrict__ HnT, const u16* __restrict__ WlT,
        const float* __restrict__ s1, const float* __restrict__ b1,
        const float* __restrict__ s2, const float* __restrict__ b2,
        float* __restrict__ Af, float* __restrict__ out) {
    __shared__ union {
        struct { u16 Qs[32 * LQT]; u16 Ks[64 * LQT];
                 u16 Bs[128 * LPT]; u16 As[32 * LPT]; } ck;   // 49152 B
        struct { u16 Ws[128 * LWT]; u16 Hs[32 * LWT]; } fin;  // 43520 B
    } sm;
    __shared__ float redS[128], redQ[128], redA[128];
    __shared__ float2 MV[32];
    __shared__ float2 cfs[32];
    int rt = blockIdx.x, b = blockIdx.y;
    int R0 = rt * 32;
    int t = threadIdx.x;
    int lane = t & 63, w = t >> 6, q = lane >> 4, r16 = lane & 15;
    int i2 = w >> 2, j2 = w & 3;      // MFMA1 wave tile (16x16)
    int wr = i2 * 16;                 // wave row base
    int wc = j2 * 32;                 // MFMA2 wave col base

    const u16* Qg = Qb + ((size_t)b * NN + R0) * DD;
    {   // stage Q once: 512 slots of 16B
        int row = t >> 4, seg = t & 15;
        *(uint4*)&sm.ck.Qs[row * LQT + seg * 8] = *(const uint4*)&Qg[row * DD + seg * 8];
    }

    const u16* Kg = Kb + (size_t)b * NN * DD;
    const u16* Bg = HnT + (size_t)b * DD * NN;
    int krow0 = t >> 4, krow1 = 32 + (t >> 4), kseg = (t & 15) * 8;
    int bd0 = t >> 3, bd1 = 64 + (t >> 3), bsg = (t & 7) * 8;
    int mloc = j2 * 16 + r16;

    // ======================= PASS 1: denominator sums =======================
    float ER0 = 0.f, ER1 = 0.f, ER2 = 0.f, ER3 = 0.f;
    float LR0 = 0.f, LR1 = 0.f, LR2 = 0.f, LR3 = 0.f;
    float LA0 = 0.f, LA1 = 0.f, LA2 = 0.f, LA3 = 0.f;

    uint4 pk0 = *(const uint4*)&Kg[(size_t)krow0 * DD + kseg];
    uint4 pk1 = *(const uint4*)&Kg[(size_t)krow1 * DD + kseg];

    for (int kc = 0; kc < NN; kc += 64) {
        __syncthreads();
        *(uint4*)&sm.ck.Ks[krow0 * LQT + kseg] = pk0;
        *(uint4*)&sm.ck.Ks[krow1 * LQT + kseg] = pk1;
        if (kc + 64 < NN) {
            int kn = kc + 64;
            pk0 = *(const uint4*)&Kg[(size_t)(kn + krow0) * DD + kseg];
            pk1 = *(const uint4*)&Kg[(size_t)(kn + krow1) * DD + kseg];
        }
        __syncthreads();
        f32x4 sa = (f32x4){0.f, 0.f, 0.f, 0.f};
#pragma unroll
        for (int ksp = 0; ksp < 4; ++ksp) {
            int ko = ksp * 32 + q * 8;
            bf16x8 a0 = *(const bf16x8*)&sm.ck.Qs[(wr + r16) * LQT + ko];
            bf16x8 b0 = *(const bf16x8*)&sm.ck.Ks[(j2 * 16 + r16) * LQT + ko];
            sa = __builtin_amdgcn_mfma_f32_16x16x32_bf16(a0, b0, sa, 0, 0, 0);
        }
        int mb = kc + mloc;
        float rm = clamp01(rel[b * NN + mb]);
        const u16* lcol = lgh + mb;
        const u16* acol = am + mb;
        {
            int n = R0 + wr + q * 4;
            float e0 = __expf(sa[0] + h2f(lcol[(size_t)(n + 0) * NN]));
            float e1 = __expf(sa[1] + h2f(lcol[(size_t)(n + 1) * NN]));
            float e2 = __expf(sa[2] + h2f(lcol[(size_t)(n + 2) * NN]));
            float e3 = __expf(sa[3] + h2f(lcol[(size_t)(n + 3) * NN]));
            float a0 = bf2f(acol[(size_t)(n + 0) * NN]);
            float a1 = bf2f(acol[(size_t)(n + 1) * NN]);
            float a2 = bf2f(acol[(size_t)(n + 2) * NN]);
            float a3 = bf2f(acol[(size_t)(n + 3) * NN]);
            ER0 += e0; ER1 += e1; ER2 += e2; ER3 += e3;
            LR0 = fmaf(e0, rm, LR0); LR1 = fmaf(e1, rm, LR1);
            LR2 = fmaf(e2, rm, LR2); LR3 = fmaf(e3, rm, LR3);
            LA0 = fmaf(a0, rm, LA0); LA1 = fmaf(a1, rm, LA1);
            LA2 = fmaf(a2, rm, LA2); LA3 = fmaf(a3, rm, LA3);
        }
    }
    // loop2 prologue prefetch — issued early so it overlaps the reduce
    pk0 = *(const uint4*)&Kg[(size_t)krow0 * DD + kseg];
    pk1 = *(const uint4*)&Kg[(size_t)krow1 * DD + kseg];
    uint4 pb0 = *(const uint4*)&Bg[(size_t)bd0 * NN + bsg];
    uint4 pb1 = *(const uint4*)&Bg[(size_t)bd1 * NN + bsg];

    // reduce over the 16 lanes of each quarter-wave
#pragma unroll
    for (int off = 1; off < 16; off <<= 1) {
        ER0 += __shfl_xor(ER0, off); ER1 += __shfl_xor(ER1, off);
        ER2 += __shfl_xor(ER2, off); ER3 += __shfl_xor(ER3, off);
        LR0 += __shfl_xor(LR0, off); LR1 += __shfl_xor(LR1, off);
        LR2 += __shfl_xor(LR2, off); LR3 += __shfl_xor(LR3, off);
        LA0 += __shfl_xor(LA0, off); LA1 += __shfl_xor(LA1, off);
        LA2 += __shfl_xor(LA2, off); LA3 += __shfl_xor(LA3, off);
    }
    if (r16 == 0) {
        int row = wr + q * 4;
        redS[j2 * 32 + row + 0] = ER0; redQ[j2 * 32 + row + 0] = LR0; redA[j2 * 32 + row + 0] = LA0;
        redS[j2 * 32 + row + 1] = ER1; redQ[j2 * 32 + row + 1] = LR1; redA[j2 * 32 + row + 1] = LA1;
        redS[j2 * 32 + row + 2] = ER2; redQ[j2 * 32 + row + 2] = LR2; redA[j2 * 32 + row + 2] = LA2;
        redS[j2 * 32 + row + 3] = ER3; redQ[j2 * 32 + row + 3] = LR3; redA[j2 * 32 + row + 3] = LA3;
    }
    __syncthreads();
    if (t < 32) {
        float es = redS[t] + redS[32 + t] + redS[64 + t] + redS[96 + t];
        float lr = redQ[t] + redQ[32 + t] + redQ[64 + t] + redQ[96 + t];
        float la = redA[t] + redA[32 + t] + redA[64 + t] + redA[96 + t];
        float rn = clamp01(rel[b * NN + R0 + t]);
        float inv = 1.f / es;                     // es > 0 (diag edge kept)
        float fsum = rn * (0.6f * lr * inv + 0.4f * la);
        float nrm = 1.f / (fsum + 1e-8f);
        cfs[t] = make_float2(0.6f * inv * rn * nrm, 0.4f * rn * nrm);
    }

    // ======================= PASS 2: A_fuse + H GEMM ========================
    f32x4 acc[2];
    acc[0] = (f32x4){0.f, 0.f, 0.f, 0.f};
    acc[1] = (f32x4){0.f, 0.f, 0.f, 0.f};

    for (int kc = 0; kc < NN; kc += 64) {
        __syncthreads();            // prev MFMA reads done; also orders cfs
        *(uint4*)&sm.ck.Ks[krow0 * LQT + kseg] = pk0;
        *(uint4*)&sm.ck.Ks[krow1 * LQT + kseg] = pk1;
        *(uint4*)&sm.ck.Bs[bd0 * LPT + bsg] = pb0;
        *(uint4*)&sm.ck.Bs[bd1 * LPT + bsg] = pb1;
        if (kc + 64 < NN) {         // prefetch next chunk (hidden under MFMA)
            int kn = kc + 64;
            pk0 = *(const uint4*)&Kg[(size_t)(kn + krow0) * DD + kseg];
            pk1 = *(const uint4*)&Kg[(size_t)(kn + krow1) * DD + kseg];
            pb0 = *(const uint4*)&Bg[(size_t)bd0 * NN + kn + bsg];
            pb1 = *(const uint4*)&Bg[(size_t)bd1 * NN + kn + bsg];
        }
        __syncthreads();
        // ---- MFMA1: S chunk (identical fragment order to pass 1)
        f32x4 sa = (f32x4){0.f, 0.f, 0.f, 0.f};
#pragma unroll
        for (int ksp = 0; ksp < 4; ++ksp) {
            int ko = ksp * 32 + q * 8;
            bf16x8 a0 = *(const bf16x8*)&sm.ck.Qs[(wr + r16) * LQT + ko];
            bf16x8 b0 = *(const bf16x8*)&sm.ck.Ks[(j2 * 16 + r16) * LQT + ko];
            sa = __builtin_amdgcn_mfma_f32_16x16x32_bf16(a0, b0, sa, 0, 0, 0);
        }
        // ---- epilogue: e, A_fuse value, global store + bf16 to As
        int mb = kc + mloc;
        float rm = clamp01(rel[b * NN + mb]);
#pragma unroll
        for (int r = 0; r < 4; ++r) {
            int nl = wr + q * 4 + r;
            int n = R0 + nl;
            float lg = h2f(lgh[(size_t)n * NN + mb]);
            float av = bf2f(am[(size_t)n * NN + mb]);
            float2 cf = cfs[nl];
            float e = __expf(sa[r] + lg);             // masked: -inf -> 0
            float v = rm * fmaf(e, cf.x, av * cf.y);
            Af[((size_t)b * NN + n) * NN + mb] = v;
            sm.ck.As[nl * LPT + mloc] = f2bf(v);
        }
        __syncthreads();
        // ---- MFMA2: H += As @ Bs
#pragma unroll
        for (int kst = 0; kst < 2; ++kst) {
            int ko = kst * 32 + q * 8;
            bf16x8 a0 = *(const bf16x8*)&sm.ck.As[(wr + r16) * LPT + ko];
            bf16x8 b0 = *(const bf16x8*)&sm.ck.Bs[(wc + r16) * LPT + ko];
            bf16x8 b1v = *(const bf16x8*)&sm.ck.Bs[(wc + 16 + r16) * LPT + ko];
            acc[0] = __builtin_amdgcn_mfma_f32_16x16x32_bf16(a0, b0, acc[0], 0, 0, 0);
            acc[1] = __builtin_amdgcn_mfma_f32_16x16x32_bf16(a0, b1v, acc[1], 0, 0, 0);
        }
    }

    // ---- fused final: H -> bf16 LDS, @W_lin, relu, LN1, LN2 ----
    __syncthreads();                // all MFMA reads done before union reuse
#pragma unroll
    for (int rep = 0; rep < 4; ++rep) {
        int e = rep * 512 + t;      // 2048 uint4 slots
        int dp = e >> 4, seg = e & 15;
        *(uint4*)&sm.fin.Ws[dp * LWT + seg * 8] = *(const uint4*)&WlT[dp * DD + seg * 8];
    }
#pragma unroll
    for (int j = 0; j < 2; ++j)
#pragma unroll
        for (int r = 0; r < 4; ++r)
            sm.fin.Hs[(wr + q * 4 + r) * LWT + wc + j * 16 + r16] = f2bf(acc[j][r]);
    __syncthreads();

    f32x4 c2[2];
    c2[0] = (f32x4){0.f, 0.f, 0.f, 0.f};
    c2[1] = (f32x4){0.f, 0.f, 0.f, 0.f};
#pragma unroll
    for (int ksp = 0; ksp < 4; ++ksp) {
        int ko = ksp * 32 + q * 8;
        bf16x8 a0 = *(const bf16x8*)&sm.fin.Hs[(wr + r16) * LWT + ko];
        bf16x8 b0 = *(const bf16x8*)&sm.fin.Ws[(wc + r16) * LWT + ko];
        bf16x8 b1v = *(const bf16x8*)&sm.fin.Ws[(wc + 16 + r16) * LWT + ko];
        c2[0] = __builtin_amdgcn_mfma_f32_16x16x32_bf16(a0, b0, c2[0], 0, 0, 0);
        c2[1] = __builtin_amdgcn_mfma_f32_16x16x32_bf16(a0, b1v, c2[1], 0, 0, 0);
    }
    float v[2][4];
#pragma unroll
    for (int j = 0; j < 2; ++j)
#pragma unroll
        for (int r = 0; r < 4; ++r)
            v[j][r] = fmaxf(c2[j][r], 0.f);

    int c0 = wc + r16, c1 = wc + 16 + r16;
    float s1c0 = s1[c0], s1c1 = s1[c1], b1c0 = b1[c0], b1c1 = b1[c1];
    float s2c0 = s2[c0], s2c1 = s2[c1], b2c0 = b2[c0], b2c1 = b2[c1];
    int g4 = (w & 3) * 32;          // reduction group offset

#pragma unroll
    for (int r = 0; r < 4; ++r) {
        float s = v[0][r] + v[1][r];
        float qq = v[0][r] * v[0][r] + v[1][r] * v[1][r];
#pragma unroll
        for (int off = 1; off < 16; off <<= 1) {
            s += __shfl_xor(s, off);
            qq += __shfl_xor(qq, off);
        }
        if (r16 == 0) {
            int row = wr + q * 4 + r;
            redS[g4 + row] = s;
            redQ[g4 + row] = qq;
        }
    }
    __syncthreads();
    if (t < 32) {
        float s = redS[t] + redS[32 + t] + redS[64 + t] + redS[96 + t];
        float qq = redQ[t] + redQ[32 + t] + redQ[64 + t] + redQ[96 + t];
        float mu = s * (1.f / 128.f);
        float var = qq * (1.f / 128.f) - mu * mu;
        MV[t] = make_float2(mu, 1.f / sqrtf(var + 1e-5f));
    }
    __syncthreads();
    float y[2][4];
#pragma unroll
    for (int r = 0; r < 4; ++r) {
        float2 mv = MV[wr + q * 4 + r];
        y[0][r] = (v[0][r] - mv.x) * mv.y * s1c0 + b1c0;
        y[1][r] = (v[1][r] - mv.x) * mv.y * s1c1 + b1c1;
    }
    __syncthreads();
#pragma unroll
    for (int r = 0; r < 4; ++r) {
        float s = y[0][r] + y[1][r];
        float qq = y[0][r] * y[0][r] + y[1][r] * y[1][r];
#pragma unroll
        for (int off = 1; off < 16; off <<= 1) {
            s += __shfl_xor(s, off);
            qq += __shfl_xor(qq, off);
        }
        if (r16 == 0) {
            int row = wr + q * 4 + r;
            redS[g4 + row] = s;
            redQ[g4 + row] = qq;
        }
    }
    __syncthreads();
    if (t < 32) {
        float s = redS[t] + redS[32 + t] + redS[64 + t] + redS[96 + t];
        float qq = redQ[t] + redQ[32 + t] + redQ[64 + t] + redQ[96 + t];
        float mu = s * (1.f / 128.f);
        float var = qq * (1.f / 128.f) - mu * mu;
        MV[t] = make_float2(mu, 1.f / sqrtf(var + 1e-5f));
    }
    __syncthreads();
#pragma unroll
    for (int r = 0; r < 4; ++r) {
        float2 mv = MV[wr + q * 4 + r];
        size_t o = ((size_t)b * NN + R0 + wr + q * 4 + r) * DD;
        out[o + c0] = (y[0][r] - mv.x) * mv.y * s2c0 + b2c0;
        out[o + c1] = (y[1][r] - mv.x) * mv.y * s2c1 + b2c1;
    }
}

extern "C" void kernel_launch(void* const* d_in, const int* in_sizes, int n_in,
                              void* d_out, int out_size, void* d_ws, size_t ws_size,
                              hipStream_t stream) {
    const float* X = (const float*)d_in[0];
    const float* Msk = (const float*)d_in[1];
    const float* Astat = (const float*)d_in[2];
    const int* Mm = (const int*)d_in[3];
    const float* rel = (const float*)d_in[4];
    const float* Wproj = (const float*)d_in[5];
    const float* Wq = (const float*)d_in[6];
    const float* Wk = (const float*)d_in[7];
    const float* Wlin = (const float*)d_in[8];
    const float* s1 = (const float*)d_in[9];
    const float* b1 = (const float*)d_in[10];
    const float* s2 = (const float*)d_in[11];
    const float* b2 = (const float*)d_in[12];

    float* outMain = (float*)d_out;                       // (B,N,D)
    float* Afuse = outMain + (size_t)BB * NN * DD;        // (B,N,N)

    float* w_ = (float*)d_ws;
    float* Wpq = w_;                                      // 4096 f
    float* Wpk = w_ + 4096;                               // 4096 f
    u16* WlT = (u16*)(w_ + 8192);                         // 16384 u16
    u16* Qb = (u16*)(w_ + 16384);                         // 2097152 u16
    u16* Kb = (u16*)(w_ + 1064960);                       // 2097152 u16
    u16* HnT = (u16*)(w_ + 2113536);                      // 2097152 u16
    u16* lgh = (u16*)(w_ + 3162112);                      // 4194304 u16 (f16)
    u16* am = (u16*)(w_ + 5259264);                       // 4194304 u16 (bf16)

    prep_kernel<<<dim3(4192), dim3(256), 0, stream>>>(
        Astat, Mm, Wproj, Wq, Wk, Wlin, lgh, am, Wpq, Wpk, WlT);
    proj3_kernel<<<dim3(512), dim3(256), 0, stream>>>(X, Msk, Wproj, Wpq, Wpk, HnT, Qb, Kb);

    prop_kernel<<<dim3(64, 8), dim3(512), 0, stream>>>(
        Qb, Kb, lgh, am, rel, HnT, WlT, s1, b1, s2, b2, Afuse, outMain);
}

// Round 9
// 307.403 us; speedup vs baseline: 1.3246x; 1.0044x over previous
//
#include <hip/hip_runtime.h>
#include <math.h>

#define BB 8
#define NN 2048
#define SS 16
#define CC 32
#define DD 128

typedef unsigned short u16;
typedef __attribute__((ext_vector_type(8))) short bf16x8;
typedef __attribute__((ext_vector_type(4))) float f32x4;

__device__ inline u16 f2bf(float f) {
    union { float f; unsigned u; } c; c.f = f;
    unsigned r = c.u + 0x7fff + ((c.u >> 16) & 1);   // round-to-nearest-even
    return (u16)(r >> 16);
}
__device__ inline float bf2f(u16 h) {
    union { unsigned u; float f; } c; c.u = ((unsigned)h) << 16;
    return c.f;
}
__device__ inline u16 f2h(float f) {
    union { _Float16 h; u16 u; } c; c.h = (_Float16)f;
    return c.u;
}
__device__ inline float h2f(u16 u) {
    union { _Float16 h; u16 v; } c; c.v = u;
    return (float)c.h;
}
__device__ inline float clamp01(float v) { return fminf(fmaxf(v, 0.f), 1.f); }

// ---------------- K1: merged prep: packed bias table + wcomb + wlt ---------
// lam[n][m] = (am_bf16 << 16) | lg_f16  — one u32 per edge (bit-identical
// unpack vs the former separate lgh/am arrays, same 16 MB total).
__global__ __launch_bounds__(256) void prep_kernel(const float* __restrict__ Astat,
                                                   const int* __restrict__ Mm,
                                                   const float* __restrict__ Wproj,
                                                   const float* __restrict__ Wq,
                                                   const float* __restrict__ Wk,
                                                   const float* __restrict__ Wl,
                                                   unsigned* __restrict__ lam,
                                                   float* __restrict__ Wpq,
                                                   float* __restrict__ Wpk,
                                                   u16* __restrict__ WlT) {
    int bx = blockIdx.x;
    if (bx < 4096) {
        size_t g = ((size_t)bx * 256 + threadIdx.x) * 4;   // 4194304 total
        float4 a4 = *(const float4*)&Astat[g];
        int4 m4 = *(const int4*)&Mm[g];
        float a[4] = {a4.x, a4.y, a4.z, a4.w};
        int mm[4] = {m4.x, m4.y, m4.z, m4.w};
        unsigned pw[4];
#pragma unroll
        for (int j = 0; j < 4; ++j) {
            float p = fminf(fmaxf(a[j], 1e-3f), 1.f - 1e-3f);
            float l = __logf(p / (1.f - p));          // ETA = 1.0
            u16 lg = mm[j] ? f2h(l) : (u16)0xFC00;    // -inf f16 when masked
            u16 ab = mm[j] ? f2bf(a[j]) : (u16)0;
            pw[j] = ((unsigned)ab << 16) | lg;
        }
        *(uint4*)&lam[g] = make_uint4(pw[0], pw[1], pw[2], pw[3]);
    } else if (bx < 4128) {
        int i = (bx - 4096) * 256 + threadIdx.x;      // 8192 outputs
        int d = i & 127;
        int c = (i >> 7) & 31;
        int mat = i >> 12;
        const float* Wt = mat ? Wk : Wq;
        float acc = 0.f;
#pragma unroll 4
        for (int e = 0; e < DD; ++e)
            acc = fmaf(Wproj[c * DD + e], Wt[e * DD + d], acc);
        (mat ? Wpk : Wpq)[c * DD + d] = acc;
    } else {
        int i = (bx - 4128) * 256 + threadIdx.x;      // 16384 outputs
        int dp = i >> 7, d = i & 127;
        WlT[dp * DD + d] = f2bf(Wl[d * DD + dp]);
    }
}

// ---------------- K3: fused pool + Hn/Q/K projections, emitted bf16 --------
__global__ __launch_bounds__(256) void proj3_kernel(const float* __restrict__ X,
                                                    const float* __restrict__ Msk,
                                                    const float* __restrict__ Wproj,
                                                    const float* __restrict__ Wpq,
                                                    const float* __restrict__ Wpk,
                                                    u16* __restrict__ HnT,
                                                    u16* __restrict__ Qb,
                                                    u16* __restrict__ Kb) {
    __shared__ float wp[CC * DD], wq[CC * DD], wk[CC * DD];
    __shared__ float xs[CC * 36];
    int t = threadIdx.x;
    for (int i = t; i < CC * DD; i += 256) {
        wp[i] = Wproj[i];
        wq[i] = Wpq[i];
        wk[i] = Wpk[i];
    }
    int rbase = blockIdx.x * 32;
    {   // masked temporal mean pooling: thread = (row, 4-col group)
        int row = t >> 3, cg = t & 7;
        const float* xrow = X + ((size_t)(rbase + row) * SS) * CC + cg * 4;
        const float* mrow = Msk + (size_t)(rbase + row) * SS;
        float4 acc = make_float4(0.f, 0.f, 0.f, 0.f);
        float msum = 0.f;
#pragma unroll
        for (int s = 0; s < SS; ++s) {
            float mv = mrow[s];
            float4 xv = *(const float4*)&xrow[s * CC];
            msum += mv;
            acc.x = fmaf(xv.x, mv, acc.x);
            acc.y = fmaf(xv.y, mv, acc.y);
            acc.z = fmaf(xv.z, mv, acc.z);
            acc.w = fmaf(xv.w, mv, acc.w);
        }
        float inv = 1.f / fmaxf(msum, 1.0f);
        xs[(cg * 4 + 0) * 36 + row] = acc.x * inv;
        xs[(cg * 4 + 1) * 36 + row] = acc.y * inv;
        xs[(cg * 4 + 2) * 36 + row] = acc.z * inv;
        xs[(cg * 4 + 3) * 36 + row] = acc.w * inv;
    }
    __syncthreads();

    int col = t & 127;
    int g = t >> 7;
    float ah[16], aq[16], ak[16];
#pragma unroll
    for (int i = 0; i < 16; ++i) { ah[i] = 0.f; aq[i] = 0.f; ak[i] = 0.f; }

#pragma unroll 4
    for (int k = 0; k < CC; ++k) {
        float wpv = wp[k * DD + col], wqv = wq[k * DD + col], wkv = wk[k * DD + col];
        const float4* xp = (const float4*)&xs[k * 36 + g * 16];
        float4 a0 = xp[0], a1 = xp[1], a2 = xp[2], a3 = xp[3];
        float xv[16] = {a0.x, a0.y, a0.z, a0.w, a1.x, a1.y, a1.z, a1.w,
                        a2.x, a2.y, a2.z, a2.w, a3.x, a3.y, a3.z, a3.w};
#pragma unroll
        for (int i = 0; i < 16; ++i) {
            ah[i] = fmaf(xv[i], wpv, ah[i]);
            aq[i] = fmaf(xv[i], wqv, aq[i]);
            ak[i] = fmaf(xv[i], wkv, ak[i]);
        }
    }
    const float scale = 0.08838834764831845f;     // 1/sqrt(128) folded into Q
#pragma unroll
    for (int i = 0; i < 16; ++i) {
        size_t row = (size_t)(rbase + g * 16 + i);
        Qb[row * DD + col] = f2bf(aq[i] * scale);
        Kb[row * DD + col] = f2bf(ak[i]);
    }
    int b = rbase >> 11;
    int n0 = (rbase & (NN - 1)) + g * 16;
    u16* hp = HnT + (size_t)b * DD * NN + (size_t)col * NN + n0;
    unsigned pk[8];
#pragma unroll
    for (int i = 0; i < 8; ++i)
        pk[i] = (unsigned)f2bf(ah[2 * i]) | ((unsigned)f2bf(ah[2 * i + 1]) << 16);
    *(uint4*)&hp[0] = make_uint4(pk[0], pk[1], pk[2], pk[3]);
    *(uint4*)&hp[8] = make_uint4(pk[4], pk[5], pk[6], pk[7]);
}

// ---------------- K5: two-pass fused attention-propagate kernel ------------
// grid (rt=64, b=8), 512 threads (8 waves). Pass 1: MFMA1 S=Q@K^T per chunk,
// accumulate ER/LR/LA -> coef. Pass 2: recompute e bitwise-identically,
// materialize A_fuse, MFMA2 H += A@Hn, fused W_lin/relu/LN1/LN2 tail.
// lam reads: 4 u32/lane/chunk (full-line coalesced), prefetched one chunk
// ahead into NAMED scalars (4 VGPRs — arrays spill, round-5 lesson).
#define LQT 136
#define LPT 72
#define LWT 136
__global__ __launch_bounds__(512) void prop_kernel(
        const u16* __restrict__ Qb, const u16* __restrict__ Kb,
        const unsigned* __restrict__ lam,
        const float* __restrict__ rel,
        const u16* __restrict__ HnT, const u16* __restrict__ WlT,
        const float* __restrict__ s1, const float* __restrict__ b1,
        const float* __restrict__ s2, const float* __restrict__ b2,
        float* __restrict__ Af, float* __restrict__ out) {
    __shared__ union {
        struct { u16 Qs[32 * LQT]; u16 Ks[64 * LQT];
                 u16 Bs[128 * LPT]; u16 As[32 * LPT]; } ck;   // 49152 B
        struct { u16 Ws[128 * LWT]; u16 Hs[32 * LWT]; } fin;  // 43520 B
    } sm;
    __shared__ float redS[128], redQ[128], redA[128];
    __shared__ float2 MV[32];
    __shared__ float2 cfs[32];
    int rt = blockIdx.x, b = blockIdx.y;
    int R0 = rt * 32;
    int t = threadIdx.x;
    int lane = t & 63, w = t >> 6, q = lane >> 4, r16 = lane & 15;
    int i2 = w >> 2, j2 = w & 3;      // MFMA1 wave tile (16x16)
    int wr = i2 * 16;                 // wave row base
    int wc = j2 * 32;                 // MFMA2 wave col base

    const u16* Qg = Qb + ((size_t)b * NN + R0) * DD;
    {   // stage Q once: 512 slots of 16B
        int row = t >> 4, seg = t & 15;
        *(uint4*)&sm.ck.Qs[row * LQT + seg * 8] = *(const uint4*)&Qg[row * DD + seg * 8];
    }

    const u16* Kg = Kb + (size_t)b * NN * DD;
    const u16* Bg = HnT + (size_t)b * DD * NN;
    int krow0 = t >> 4, krow1 = 32 + (t >> 4), kseg = (t & 15) * 8;
    int bd0 = t >> 3, bd1 = 64 + (t >> 3), bsg = (t & 7) * 8;
    int mloc = j2 * 16 + r16;
    int n0 = R0 + wr + q * 4;
    const size_t lb0 = (size_t)n0 * NN + mloc;    // lam base (row n0, col mloc)

    // ======================= PASS 1: denominator sums =======================
    float ER0 = 0.f, ER1 = 0.f, ER2 = 0.f, ER3 = 0.f;
    float LR0 = 0.f, LR1 = 0.f, LR2 = 0.f, LR3 = 0.f;
    float LA0 = 0.f, LA1 = 0.f, LA2 = 0.f, LA3 = 0.f;

    uint4 pk0 = *(const uint4*)&Kg[(size_t)krow0 * DD + kseg];
    uint4 pk1 = *(const uint4*)&Kg[(size_t)krow1 * DD + kseg];
    unsigned pl0 = lam[lb0];
    unsigned pl1 = lam[lb0 + NN];
    unsigned pl2 = lam[lb0 + 2 * NN];
    unsigned pl3 = lam[lb0 + 3 * NN];

    for (int kc = 0; kc < NN; kc += 64) {
        __syncthreads();
        *(uint4*)&sm.ck.Ks[krow0 * LQT + kseg] = pk0;
        *(uint4*)&sm.ck.Ks[krow1 * LQT + kseg] = pk1;
        if (kc + 64 < NN) {
            int kn = kc + 64;
            pk0 = *(const uint4*)&Kg[(size_t)(kn + krow0) * DD + kseg];
            pk1 = *(const uint4*)&Kg[(size_t)(kn + krow1) * DD + kseg];
        }
        __syncthreads();
        f32x4 sa = (f32x4){0.f, 0.f, 0.f, 0.f};
#pragma unroll
        for (int ksp = 0; ksp < 4; ++ksp) {
            int ko = ksp * 32 + q * 8;
            bf16x8 a0 = *(const bf16x8*)&sm.ck.Qs[(wr + r16) * LQT + ko];
            bf16x8 b0 = *(const bf16x8*)&sm.ck.Ks[(j2 * 16 + r16) * LQT + ko];
            sa = __builtin_amdgcn_mfma_f32_16x16x32_bf16(a0, b0, sa, 0, 0, 0);
        }
        int mb = kc + mloc;
        float rm = clamp01(rel[b * NN + mb]);
        float e0 = __expf(sa[0] + h2f((u16)(pl0 & 0xffff)));
        float a0v = bf2f((u16)(pl0 >> 16));
        float e1 = __expf(sa[1] + h2f((u16)(pl1 & 0xffff)));
        float a1v = bf2f((u16)(pl1 >> 16));
        float e2 = __expf(sa[2] + h2f((u16)(pl2 & 0xffff)));
        float a2v = bf2f((u16)(pl2 >> 16));
        float e3 = __expf(sa[3] + h2f((u16)(pl3 & 0xffff)));
        float a3v = bf2f((u16)(pl3 >> 16));
        ER0 += e0; ER1 += e1; ER2 += e2; ER3 += e3;
        LR0 = fmaf(e0, rm, LR0); LR1 = fmaf(e1, rm, LR1);
        LR2 = fmaf(e2, rm, LR2); LR3 = fmaf(e3, rm, LR3);
        LA0 = fmaf(a0v, rm, LA0); LA1 = fmaf(a1v, rm, LA1);
        LA2 = fmaf(a2v, rm, LA2); LA3 = fmaf(a3v, rm, LA3);
        if (kc + 64 < NN) {         // prefetch next chunk's lam words
            size_t lb = lb0 + (kc + 64);
            pl0 = lam[lb];
            pl1 = lam[lb + NN];
            pl2 = lam[lb + 2 * NN];
            pl3 = lam[lb + 3 * NN];
        }
    }
    // pass-2 prologue prefetch — issued early so it overlaps the reduce
    pk0 = *(const uint4*)&Kg[(size_t)krow0 * DD + kseg];
    pk1 = *(const uint4*)&Kg[(size_t)krow1 * DD + kseg];
    uint4 pb0 = *(const uint4*)&Bg[(size_t)bd0 * NN + bsg];
    uint4 pb1 = *(const uint4*)&Bg[(size_t)bd1 * NN + bsg];
    pl0 = lam[lb0];
    pl1 = lam[lb0 + NN];
    pl2 = lam[lb0 + 2 * NN];
    pl3 = lam[lb0 + 3 * NN];

    // reduce over the 16 lanes of each quarter-wave
#pragma unroll
    for (int off = 1; off < 16; off <<= 1) {
        ER0 += __shfl_xor(ER0, off); ER1 += __shfl_xor(ER1, off);
        ER2 += __shfl_xor(ER2, off); ER3 += __shfl_xor(ER3, off);
        LR0 += __shfl_xor(LR0, off); LR1 += __shfl_xor(LR1, off);
        LR2 += __shfl_xor(LR2, off); LR3 += __shfl_xor(LR3, off);
        LA0 += __shfl_xor(LA0, off); LA1 += __shfl_xor(LA1, off);
        LA2 += __shfl_xor(LA2, off); LA3 += __shfl_xor(LA3, off);
    }
    if (r16 == 0) {
        int row = wr + q * 4;
        redS[j2 * 32 + row + 0] = ER0; redQ[j2 * 32 + row + 0] = LR0; redA[j2 * 32 + row + 0] = LA0;
        redS[j2 * 32 + row + 1] = ER1; redQ[j2 * 32 + row + 1] = LR1; redA[j2 * 32 + row + 1] = LA1;
        redS[j2 * 32 + row + 2] = ER2; redQ[j2 * 32 + row + 2] = LR2; redA[j2 * 32 + row + 2] = LA2;
        redS[j2 * 32 + row + 3] = ER3; redQ[j2 * 32 + row + 3] = LR3; redA[j2 * 32 + row + 3] = LA3;
    }
    __syncthreads();
    if (t < 32) {
        float es = redS[t] + redS[32 + t] + redS[64 + t] + redS[96 + t];
        float lr = redQ[t] + redQ[32 + t] + redQ[64 + t] + redQ[96 + t];
        float la = redA[t] + redA[32 + t] + redA[64 + t] + redA[96 + t];
        float rn = clamp01(rel[b * NN + R0 + t]);
        float inv = 1.f / es;                     // es > 0 (diag edge kept)
        float fsum = rn * (0.6f * lr * inv + 0.4f * la);
        float nrm = 1.f / (fsum + 1e-8f);
        cfs[t] = make_float2(0.6f * inv * rn * nrm, 0.4f * rn * nrm);
    }

    // ======================= PASS 2: A_fuse + H GEMM ========================
    f32x4 acc[2];
    acc[0] = (f32x4){0.f, 0.f, 0.f, 0.f};
    acc[1] = (f32x4){0.f, 0.f, 0.f, 0.f};

    for (int kc = 0; kc < NN; kc += 64) {
        __syncthreads();            // prev MFMA reads done; also orders cfs
        *(uint4*)&sm.ck.Ks[krow0 * LQT + kseg] = pk0;
        *(uint4*)&sm.ck.Ks[krow1 * LQT + kseg] = pk1;
        *(uint4*)&sm.ck.Bs[bd0 * LPT + bsg] = pb0;
        *(uint4*)&sm.ck.Bs[bd1 * LPT + bsg] = pb1;
        if (kc + 64 < NN) {         // prefetch next chunk (hidden under MFMA)
            int kn = kc + 64;
            pk0 = *(const uint4*)&Kg[(size_t)(kn + krow0) * DD + kseg];
            pk1 = *(const uint4*)&Kg[(size_t)(kn + krow1) * DD + kseg];
            pb0 = *(const uint4*)&Bg[(size_t)bd0 * NN + kn + bsg];
            pb1 = *(const uint4*)&Bg[(size_t)bd1 * NN + kn + bsg];
        }
        __syncthreads();
        // ---- MFMA1: S chunk (identical fragment order to pass 1)
        f32x4 sa = (f32x4){0.f, 0.f, 0.f, 0.f};
#pragma unroll
        for (int ksp = 0; ksp < 4; ++ksp) {
            int ko = ksp * 32 + q * 8;
            bf16x8 a0 = *(const bf16x8*)&sm.ck.Qs[(wr + r16) * LQT + ko];
            bf16x8 b0 = *(const bf16x8*)&sm.ck.Ks[(j2 * 16 + r16) * LQT + ko];
            sa = __builtin_amdgcn_mfma_f32_16x16x32_bf16(a0, b0, sa, 0, 0, 0);
        }
        // ---- epilogue: e, A_fuse value, global store + bf16 to As
        int mb = kc + mloc;
        float rm = clamp01(rel[b * NN + mb]);
        float2 cf0 = cfs[wr + q * 4 + 0];
        float2 cf1 = cfs[wr + q * 4 + 1];
        float2 cf2 = cfs[wr + q * 4 + 2];
        float2 cf3 = cfs[wr + q * 4 + 3];
        float e0 = __expf(sa[0] + h2f((u16)(pl0 & 0xffff)));
        float v0 = rm * fmaf(e0, cf0.x, bf2f((u16)(pl0 >> 16)) * cf0.y);
        float e1 = __expf(sa[1] + h2f((u16)(pl1 & 0xffff)));
        float v1 = rm * fmaf(e1, cf1.x, bf2f((u16)(pl1 >> 16)) * cf1.y);
        float e2 = __expf(sa[2] + h2f((u16)(pl2 & 0xffff)));
        float v2 = rm * fmaf(e2, cf2.x, bf2f((u16)(pl2 >> 16)) * cf2.y);
        float e3 = __expf(sa[3] + h2f((u16)(pl3 & 0xffff)));
        float v3 = rm * fmaf(e3, cf3.x, bf2f((u16)(pl3 >> 16)) * cf3.y);
        size_t ob = ((size_t)b * NN + n0) * NN + mb;
        Af[ob] = v0;
        Af[ob + NN] = v1;
        Af[ob + 2 * NN] = v2;
        Af[ob + 3 * NN] = v3;
        sm.ck.As[(wr + q * 4 + 0) * LPT + mloc] = f2bf(v0);
        sm.ck.As[(wr + q * 4 + 1) * LPT + mloc] = f2bf(v1);
        sm.ck.As[(wr + q * 4 + 2) * LPT + mloc] = f2bf(v2);
        sm.ck.As[(wr + q * 4 + 3) * LPT + mloc] = f2bf(v3);
        if (kc + 64 < NN) {         // prefetch next chunk's lam words
            size_t lb = lb0 + (kc + 64);
            pl0 = lam[lb];
            pl1 = lam[lb + NN];
            pl2 = lam[lb + 2 * NN];
            pl3 = lam[lb + 3 * NN];
        }
        __syncthreads();
        // ---- MFMA2: H += As @ Bs
#pragma unroll
        for (int kst = 0; kst < 2; ++kst) {
            int ko = kst * 32 + q * 8;
            bf16x8 a0 = *(const bf16x8*)&sm.ck.As[(wr + r16) * LPT + ko];
            bf16x8 b0 = *(const bf16x8*)&sm.ck.Bs[(wc + r16) * LPT + ko];
            bf16x8 b1v = *(const bf16x8*)&sm.ck.Bs[(wc + 16 + r16) * LPT + ko];
            acc[0] = __builtin_amdgcn_mfma_f32_16x16x32_bf16(a0, b0, acc[0], 0, 0, 0);
            acc[1] = __builtin_amdgcn_mfma_f32_16x16x32_bf16(a0, b1v, acc[1], 0, 0, 0);
        }
    }

    // ---- fused final: H -> bf16 LDS, @W_lin, relu, LN1, LN2 ----
    __syncthreads();                // all MFMA reads done before union reuse
#pragma unroll
    for (int rep = 0; rep < 4; ++rep) {
        int e = rep * 512 + t;      // 2048 uint4 slots
        int dp = e >> 4, seg = e & 15;
        *(uint4*)&sm.fin.Ws[dp * LWT + seg * 8] = *(const uint4*)&WlT[dp * DD + seg * 8];
    }
#pragma unroll
    for (int j = 0; j < 2; ++j)
#pragma unroll
        for (int r = 0; r < 4; ++r)
            sm.fin.Hs[(wr + q * 4 + r) * LWT + wc + j * 16 + r16] = f2bf(acc[j][r]);
    __syncthreads();

    f32x4 c2[2];
    c2[0] = (f32x4){0.f, 0.f, 0.f, 0.f};
    c2[1] = (f32x4){0.f, 0.f, 0.f, 0.f};
#pragma unroll
    for (int ksp = 0; ksp < 4; ++ksp) {
        int ko = ksp * 32 + q * 8;
        bf16x8 a0 = *(const bf16x8*)&sm.fin.Hs[(wr + r16) * LWT + ko];
        bf16x8 b0 = *(const bf16x8*)&sm.fin.Ws[(wc + r16) * LWT + ko];
        bf16x8 b1v = *(const bf16x8*)&sm.fin.Ws[(wc + 16 + r16) * LWT + ko];
        c2[0] = __builtin_amdgcn_mfma_f32_16x16x32_bf16(a0, b0, c2[0], 0, 0, 0);
        c2[1] = __builtin_amdgcn_mfma_f32_16x16x32_bf16(a0, b1v, c2[1], 0, 0, 0);
    }
    float v[2][4];
#pragma unroll
    for (int j = 0; j < 2; ++j)
#pragma unroll
        for (int r = 0; r < 4; ++r)
            v[j][r] = fmaxf(c2[j][r], 0.f);

    int c0 = wc + r16, c1 = wc + 16 + r16;
    float s1c0 = s1[c0], s1c1 = s1[c1], b1c0 = b1[c0], b1c1 = b1[c1];
    float s2c0 = s2[c0], s2c1 = s2[c1], b2c0 = b2[c0], b2c1 = b2[c1];
    int g4 = (w & 3) * 32;          // reduction group offset

#pragma unroll
    for (int r = 0; r < 4; ++r) {
        float s = v[0][r] + v[1][r];
        float qq = v[0][r] * v[0][r] + v[1][r] * v[1][r];
#pragma unroll
        for (int off = 1; off < 16; off <<= 1) {
            s += __shfl_xor(s, off);
            qq += __shfl_xor(qq, off);
        }
        if (r16 == 0) {
            int row = wr + q * 4 + r;
            redS[g4 + row] = s;
            redQ[g4 + row] = qq;
        }
    }
    __syncthreads();
    if (t < 32) {
        float s = redS[t] + redS[32 + t] + redS[64 + t] + redS[96 + t];
        float qq = redQ[t] + redQ[32 + t] + redQ[64 + t] + redQ[96 + t];
        float mu = s * (1.f / 128.f);
        float var = qq * (1.f / 128.f) - mu * mu;
        MV[t] = make_float2(mu, 1.f / sqrtf(var + 1e-5f));
    }
    __syncthreads();
    float y[2][4];
#pragma unroll
    for (int r = 0; r < 4; ++r) {
        float2 mv = MV[wr + q * 4 + r];
        y[0][r] = (v[0][r] - mv.x) * mv.y * s1c0 + b1c0;
        y[1][r] = (v[1][r] - mv.x) * mv.y * s1c1 + b1c1;
    }
    __syncthreads();
#pragma unroll
    for (int r = 0; r < 4; ++r) {
        float s = y[0][r] + y[1][r];
        float qq = y[0][r] * y[0][r] + y[1][r] * y[1][r];
#pragma unroll
        for (int off = 1; off < 16; off <<= 1) {
            s += __shfl_xor(s, off);
            qq += __shfl_xor(qq, off);
        }
        if (r16 == 0) {
            int row = wr + q * 4 + r;
            redS[g4 + row] = s;
            redQ[g4 + row] = qq;
        }
    }
    __syncthreads();
    if (t < 32) {
        float s = redS[t] + redS[32 + t] + redS[64 + t] + redS[96 + t];
        float qq = redQ[t] + redQ[32 + t] + redQ[64 + t] + redQ[96 + t];
        float mu = s * (1.f / 128.f);
        float var = qq * (1.f / 128.f) - mu * mu;
        MV[t] = make_float2(mu, 1.f / sqrtf(var + 1e-5f));
    }
    __syncthreads();
#pragma unroll
    for (int r = 0; r < 4; ++r) {
        float2 mv = MV[wr + q * 4 + r];
        size_t o = ((size_t)b * NN + R0 + wr + q * 4 + r) * DD;
        out[o + c0] = (y[0][r] - mv.x) * mv.y * s2c0 + b2c0;
        out[o + c1] = (y[1][r] - mv.x) * mv.y * s2c1 + b2c1;
    }
}

extern "C" void kernel_launch(void* const* d_in, const int* in_sizes, int n_in,
                              void* d_out, int out_size, void* d_ws, size_t ws_size,
                              hipStream_t stream) {
    const float* X = (const float*)d_in[0];
    const float* Msk = (const float*)d_in[1];
    const float* Astat = (const float*)d_in[2];
    const int* Mm = (const int*)d_in[3];
    const float* rel = (const float*)d_in[4];
    const float* Wproj = (const float*)d_in[5];
    const float* Wq = (const float*)d_in[6];
    const float* Wk = (const float*)d_in[7];
    const float* Wlin = (const float*)d_in[8];
    const float* s1 = (const float*)d_in[9];
    const float* b1 = (const float*)d_in[10];
    const float* s2 = (const float*)d_in[11];
    const float* b2 = (const float*)d_in[12];

    float* outMain = (float*)d_out;                       // (B,N,D)
    float* Afuse = outMain + (size_t)BB * NN * DD;        // (B,N,N)

    float* w_ = (float*)d_ws;
    float* Wpq = w_;                                      // 4096 f
    float* Wpk = w_ + 4096;                               // 4096 f
    u16* WlT = (u16*)(w_ + 8192);                         // 16384 u16
    u16* Qb = (u16*)(w_ + 16384);                         // 2097152 u16
    u16* Kb = (u16*)(w_ + 1064960);                       // 2097152 u16
    u16* HnT = (u16*)(w_ + 2113536);                      // 2097152 u16
    unsigned* lam = (unsigned*)(w_ + 3162112);            // 4194304 u32 (16 MB)

    prep_kernel<<<dim3(4192), dim3(256), 0, stream>>>(
        Astat, Mm, Wproj, Wq, Wk, Wlin, lam, Wpq, Wpk, WlT);
    proj3_kernel<<<dim3(512), dim3(256), 0, stream>>>(X, Msk, Wproj, Wpq, Wpk, HnT, Qb, Kb);

    prop_kernel<<<dim3(64, 8), dim3(512), 0, stream>>>(
        Qb, Kb, lam, rel, HnT, WlT, s1, b1, s2, b2, Afuse, outMain);
}

// Round 10
// 296.203 us; speedup vs baseline: 1.3746x; 1.0378x over previous
//
#include <hip/hip_runtime.h>
#include <math.h>

#define BB 8
#define NN 2048
#define SS 16
#define CC 32
#define DD 128

typedef unsigned short u16;
typedef __attribute__((ext_vector_type(8))) short bf16x8;
typedef __attribute__((ext_vector_type(4))) float f32x4;

__device__ inline u16 f2bf(float f) {
    union { float f; unsigned u; } c; c.f = f;
    unsigned r = c.u + 0x7fff + ((c.u >> 16) & 1);   // round-to-nearest-even
    return (u16)(r >> 16);
}
__device__ inline float bf2f(u16 h) {
    union { unsigned u; float f; } c; c.u = ((unsigned)h) << 16;
    return c.f;
}
__device__ inline u16 f2h(float f) {
    union { _Float16 h; u16 u; } c; c.h = (_Float16)f;
    return c.u;
}
__device__ inline float h2f(u16 u) {
    union { _Float16 h; u16 v; } c; c.v = u;
    return (float)c.h;
}
__device__ inline float clamp01(float v) { return fminf(fmaxf(v, 0.f), 1.f); }

// ---------------- K1: merged prep: packed bias table + wcomb + wlt ---------
__global__ __launch_bounds__(256) void prep_kernel(const float* __restrict__ Astat,
                                                   const int* __restrict__ Mm,
                                                   const float* __restrict__ Wproj,
                                                   const float* __restrict__ Wq,
                                                   const float* __restrict__ Wk,
                                                   const float* __restrict__ Wl,
                                                   unsigned* __restrict__ lam,
                                                   float* __restrict__ Wpq,
                                                   float* __restrict__ Wpk,
                                                   u16* __restrict__ WlT) {
    int bx = blockIdx.x;
    if (bx < 4096) {
        size_t g = ((size_t)bx * 256 + threadIdx.x) * 4;   // 4194304 total
        float4 a4 = *(const float4*)&Astat[g];
        int4 m4 = *(const int4*)&Mm[g];
        float a[4] = {a4.x, a4.y, a4.z, a4.w};
        int mm[4] = {m4.x, m4.y, m4.z, m4.w};
        unsigned pw[4];
#pragma unroll
        for (int j = 0; j < 4; ++j) {
            float p = fminf(fmaxf(a[j], 1e-3f), 1.f - 1e-3f);
            float l = __logf(p / (1.f - p));          // ETA = 1.0
            u16 lg = mm[j] ? f2h(l) : (u16)0xFC00;    // -inf f16 when masked
            u16 ab = mm[j] ? f2bf(a[j]) : (u16)0;
            pw[j] = ((unsigned)ab << 16) | lg;
        }
        *(uint4*)&lam[g] = make_uint4(pw[0], pw[1], pw[2], pw[3]);
    } else if (bx < 4128) {
        int i = (bx - 4096) * 256 + threadIdx.x;      // 8192 outputs
        int d = i & 127;
        int c = (i >> 7) & 31;
        int mat = i >> 12;
        const float* Wt = mat ? Wk : Wq;
        float acc = 0.f;
#pragma unroll 4
        for (int e = 0; e < DD; ++e)
            acc = fmaf(Wproj[c * DD + e], Wt[e * DD + d], acc);
        (mat ? Wpk : Wpq)[c * DD + d] = acc;
    } else {
        int i = (bx - 4128) * 256 + threadIdx.x;      // 16384 outputs
        int dp = i >> 7, d = i & 127;
        WlT[dp * DD + d] = f2bf(Wl[d * DD + dp]);
    }
}

// ---------------- K3: fused pool + Hn/Q/K projections, emitted bf16 --------
__global__ __launch_bounds__(256) void proj3_kernel(const float* __restrict__ X,
                                                    const float* __restrict__ Msk,
                                                    const float* __restrict__ Wproj,
                                                    const float* __restrict__ Wpq,
                                                    const float* __restrict__ Wpk,
                                                    u16* __restrict__ HnT,
                                                    u16* __restrict__ Qb,
                                                    u16* __restrict__ Kb) {
    __shared__ float wp[CC * DD], wq[CC * DD], wk[CC * DD];
    __shared__ float xs[CC * 36];
    int t = threadIdx.x;
    for (int i = t; i < CC * DD; i += 256) {
        wp[i] = Wproj[i];
        wq[i] = Wpq[i];
        wk[i] = Wpk[i];
    }
    int rbase = blockIdx.x * 32;
    {   // masked temporal mean pooling: thread = (row, 4-col group)
        int row = t >> 3, cg = t & 7;
        const float* xrow = X + ((size_t)(rbase + row) * SS) * CC + cg * 4;
        const float* mrow = Msk + (size_t)(rbase + row) * SS;
        float4 acc = make_float4(0.f, 0.f, 0.f, 0.f);
        float msum = 0.f;
#pragma unroll
        for (int s = 0; s < SS; ++s) {
            float mv = mrow[s];
            float4 xv = *(const float4*)&xrow[s * CC];
            msum += mv;
            acc.x = fmaf(xv.x, mv, acc.x);
            acc.y = fmaf(xv.y, mv, acc.y);
            acc.z = fmaf(xv.z, mv, acc.z);
            acc.w = fmaf(xv.w, mv, acc.w);
        }
        float inv = 1.f / fmaxf(msum, 1.0f);
        xs[(cg * 4 + 0) * 36 + row] = acc.x * inv;
        xs[(cg * 4 + 1) * 36 + row] = acc.y * inv;
        xs[(cg * 4 + 2) * 36 + row] = acc.z * inv;
        xs[(cg * 4 + 3) * 36 + row] = acc.w * inv;
    }
    __syncthreads();

    int col = t & 127;
    int g = t >> 7;
    float ah[16], aq[16], ak[16];
#pragma unroll
    for (int i = 0; i < 16; ++i) { ah[i] = 0.f; aq[i] = 0.f; ak[i] = 0.f; }

#pragma unroll 4
    for (int k = 0; k < CC; ++k) {
        float wpv = wp[k * DD + col], wqv = wq[k * DD + col], wkv = wk[k * DD + col];
        const float4* xp = (const float4*)&xs[k * 36 + g * 16];
        float4 a0 = xp[0], a1 = xp[1], a2 = xp[2], a3 = xp[3];
        float xv[16] = {a0.x, a0.y, a0.z, a0.w, a1.x, a1.y, a1.z, a1.w,
                        a2.x, a2.y, a2.z, a2.w, a3.x, a3.y, a3.z, a3.w};
#pragma unroll
        for (int i = 0; i < 16; ++i) {
            ah[i] = fmaf(xv[i], wpv, ah[i]);
            aq[i] = fmaf(xv[i], wqv, aq[i]);
            ak[i] = fmaf(xv[i], wkv, ak[i]);
        }
    }
    const float scale = 0.08838834764831845f;     // 1/sqrt(128) folded into Q
#pragma unroll
    for (int i = 0; i < 16; ++i) {
        size_t row = (size_t)(rbase + g * 16 + i);
        Qb[row * DD + col] = f2bf(aq[i] * scale);
        Kb[row * DD + col] = f2bf(ak[i]);
    }
    int b = rbase >> 11;
    int n0 = (rbase & (NN - 1)) + g * 16;
    u16* hp = HnT + (size_t)b * DD * NN + (size_t)col * NN + n0;
    unsigned pk[8];
#pragma unroll
    for (int i = 0; i < 8; ++i)
        pk[i] = (unsigned)f2bf(ah[2 * i]) | ((unsigned)f2bf(ah[2 * i + 1]) << 16);
    *(uint4*)&hp[0] = make_uint4(pk[0], pk[1], pk[2], pk[3]);
    *(uint4*)&hp[8] = make_uint4(pk[4], pk[5], pk[6], pk[7]);
}

// ---------------- K5: two-pass fused attention-propagate kernel ------------
// grid (rt=64, b=8), 512 threads (8 waves). Pipeline v2:
//  - Q fragments register-resident (loaded once, reused 64 chunk iters)
//  - Ks/Bs double-buffered: staging writes to alt buffer overlap MFMA on
//    current buffer. Barriers per chunk: pass1 = 1, pass2 = 2 (was 2/3).
//  - 2-deep prefetch: regs hold chunk i+2, alt-LDS holds chunk i+1.
#define LQT 136
#define LPT 72
#define LWT 136
__global__ __launch_bounds__(512) void prop_kernel(
        const u16* __restrict__ Qb, const u16* __restrict__ Kb,
        const unsigned* __restrict__ lam,
        const float* __restrict__ rel,
        const u16* __restrict__ HnT, const u16* __restrict__ WlT,
        const float* __restrict__ s1, const float* __restrict__ b1,
        const float* __restrict__ s2, const float* __restrict__ b2,
        float* __restrict__ Af, float* __restrict__ out) {
    __shared__ union {
        struct { u16 Ks[2][64 * LQT]; u16 Bs[2][128 * LPT];
                 u16 As[32 * LPT]; } ck;                      // 76288 B
        struct { u16 Ws[128 * LWT]; u16 Hs[32 * LWT]; } fin;  // 43520 B
    } sm;
    __shared__ float redS[128], redQ[128], redA[128];
    __shared__ float2 MV[32];
    __shared__ float2 cfs[32];
    int rt = blockIdx.x, b = blockIdx.y;
    int R0 = rt * 32;
    int t = threadIdx.x;
    int lane = t & 63, w = t >> 6, q = lane >> 4, r16 = lane & 15;
    int i2 = w >> 2, j2 = w & 3;      // MFMA1 wave tile (16x16)
    int wr = i2 * 16;                 // wave row base
    int wc = j2 * 32;                 // MFMA2 wave col base

    const u16* Kg = Kb + (size_t)b * NN * DD;
    const u16* Bg = HnT + (size_t)b * DD * NN;
    int krow0 = t >> 4, krow1 = 32 + (t >> 4), kseg = (t & 15) * 8;
    int bd0 = t >> 3, bd1 = 64 + (t >> 3), bsg = (t & 7) * 8;
    int mloc = j2 * 16 + r16;
    int n0 = R0 + wr + q * 4;
    const size_t lb0 = (size_t)n0 * NN + mloc;    // lam base (row n0, col mloc)

    // Q fragments: row wr+r16 of this block's Q tile, 4x bf16x8 (16 VGPRs),
    // reused across all chunks of both passes (replaces the Qs LDS tile).
    const u16* qrow = Qb + ((size_t)b * NN + R0 + wr + r16) * DD;
    bf16x8 qf0 = *(const bf16x8*)&qrow[q * 8];
    bf16x8 qf1 = *(const bf16x8*)&qrow[32 + q * 8];
    bf16x8 qf2 = *(const bf16x8*)&qrow[64 + q * 8];
    bf16x8 qf3 = *(const bf16x8*)&qrow[96 + q * 8];

    // ======================= PASS 1: denominator sums =======================
    float ER0 = 0.f, ER1 = 0.f, ER2 = 0.f, ER3 = 0.f;
    float LR0 = 0.f, LR1 = 0.f, LR2 = 0.f, LR3 = 0.f;
    float LA0 = 0.f, LA1 = 0.f, LA2 = 0.f, LA3 = 0.f;

    // prologue: chunk0 -> Ks[0]; chunk1 -> regs; lam chunk0 -> pl
    uint4 rk0 = *(const uint4*)&Kg[(size_t)krow0 * DD + kseg];
    uint4 rk1 = *(const uint4*)&Kg[(size_t)krow1 * DD + kseg];
    *(uint4*)&sm.ck.Ks[0][krow0 * LQT + kseg] = rk0;
    *(uint4*)&sm.ck.Ks[0][krow1 * LQT + kseg] = rk1;
    rk0 = *(const uint4*)&Kg[(size_t)(64 + krow0) * DD + kseg];
    rk1 = *(const uint4*)&Kg[(size_t)(64 + krow1) * DD + kseg];
    unsigned pl0 = lam[lb0];
    unsigned pl1 = lam[lb0 + NN];
    unsigned pl2 = lam[lb0 + 2 * NN];
    unsigned pl3 = lam[lb0 + 3 * NN];
    __syncthreads();

    for (int ic = 0; ic < 32; ++ic) {
        const int p = ic & 1;
        const u16* Kc = sm.ck.Ks[p];
        u16* Kn = sm.ck.Ks[p ^ 1];
        if (ic + 1 < 32) {            // write chunk ic+1 to alt buffer
            *(uint4*)&Kn[krow0 * LQT + kseg] = rk0;
            *(uint4*)&Kn[krow1 * LQT + kseg] = rk1;
        }
        if (ic + 2 < 32) {            // prefetch chunk ic+2 to regs
            int kn2 = (ic + 2) * 64;
            rk0 = *(const uint4*)&Kg[(size_t)(kn2 + krow0) * DD + kseg];
            rk1 = *(const uint4*)&Kg[(size_t)(kn2 + krow1) * DD + kseg];
        }
        // MFMA1 on current buffer (Q in regs)
        f32x4 sa = (f32x4){0.f, 0.f, 0.f, 0.f};
        {
            const u16* kr = &Kc[(j2 * 16 + r16) * LQT + q * 8];
            bf16x8 b0 = *(const bf16x8*)&kr[0];
            sa = __builtin_amdgcn_mfma_f32_16x16x32_bf16(qf0, b0, sa, 0, 0, 0);
            b0 = *(const bf16x8*)&kr[32];
            sa = __builtin_amdgcn_mfma_f32_16x16x32_bf16(qf1, b0, sa, 0, 0, 0);
            b0 = *(const bf16x8*)&kr[64];
            sa = __builtin_amdgcn_mfma_f32_16x16x32_bf16(qf2, b0, sa, 0, 0, 0);
            b0 = *(const bf16x8*)&kr[96];
            sa = __builtin_amdgcn_mfma_f32_16x16x32_bf16(qf3, b0, sa, 0, 0, 0);
        }
        int mb = ic * 64 + mloc;
        float rm = clamp01(rel[b * NN + mb]);
        float e0 = __expf(sa[0] + h2f((u16)(pl0 & 0xffff)));
        float a0v = bf2f((u16)(pl0 >> 16));
        float e1 = __expf(sa[1] + h2f((u16)(pl1 & 0xffff)));
        float a1v = bf2f((u16)(pl1 >> 16));
        float e2 = __expf(sa[2] + h2f((u16)(pl2 & 0xffff)));
        float a2v = bf2f((u16)(pl2 >> 16));
        float e3 = __expf(sa[3] + h2f((u16)(pl3 & 0xffff)));
        float a3v = bf2f((u16)(pl3 >> 16));
        ER0 += e0; ER1 += e1; ER2 += e2; ER3 += e3;
        LR0 = fmaf(e0, rm, LR0); LR1 = fmaf(e1, rm, LR1);
        LR2 = fmaf(e2, rm, LR2); LR3 = fmaf(e3, rm, LR3);
        LA0 = fmaf(a0v, rm, LA0); LA1 = fmaf(a1v, rm, LA1);
        LA2 = fmaf(a2v, rm, LA2); LA3 = fmaf(a3v, rm, LA3);
        if (ic + 1 < 32) {            // lam for chunk ic+1
            size_t lb = lb0 + (ic + 1) * 64;
            pl0 = lam[lb];
            pl1 = lam[lb + NN];
            pl2 = lam[lb + 2 * NN];
            pl3 = lam[lb + 3 * NN];
        }
        __syncthreads();              // one barrier per pass-1 chunk
    }

    // pass-2 prologue loads issued early (overlap the reduce)
    rk0 = *(const uint4*)&Kg[(size_t)krow0 * DD + kseg];
    rk1 = *(const uint4*)&Kg[(size_t)krow1 * DD + kseg];
    uint4 rb0 = *(const uint4*)&Bg[(size_t)bd0 * NN + bsg];
    uint4 rb1 = *(const uint4*)&Bg[(size_t)bd1 * NN + bsg];
    pl0 = lam[lb0];
    pl1 = lam[lb0 + NN];
    pl2 = lam[lb0 + 2 * NN];
    pl3 = lam[lb0 + 3 * NN];

    // reduce over the 16 lanes of each quarter-wave
#pragma unroll
    for (int off = 1; off < 16; off <<= 1) {
        ER0 += __shfl_xor(ER0, off); ER1 += __shfl_xor(ER1, off);
        ER2 += __shfl_xor(ER2, off); ER3 += __shfl_xor(ER3, off);
        LR0 += __shfl_xor(LR0, off); LR1 += __shfl_xor(LR1, off);
        LR2 += __shfl_xor(LR2, off); LR3 += __shfl_xor(LR3, off);
        LA0 += __shfl_xor(LA0, off); LA1 += __shfl_xor(LA1, off);
        LA2 += __shfl_xor(LA2, off); LA3 += __shfl_xor(LA3, off);
    }
    if (r16 == 0) {
        int row = wr + q * 4;
        redS[j2 * 32 + row + 0] = ER0; redQ[j2 * 32 + row + 0] = LR0; redA[j2 * 32 + row + 0] = LA0;
        redS[j2 * 32 + row + 1] = ER1; redQ[j2 * 32 + row + 1] = LR1; redA[j2 * 32 + row + 1] = LA1;
        redS[j2 * 32 + row + 2] = ER2; redQ[j2 * 32 + row + 2] = LR2; redA[j2 * 32 + row + 2] = LA2;
        redS[j2 * 32 + row + 3] = ER3; redQ[j2 * 32 + row + 3] = LR3; redA[j2 * 32 + row + 3] = LA3;
    }
    __syncthreads();
    if (t < 32) {
        float es = redS[t] + redS[32 + t] + redS[64 + t] + redS[96 + t];
        float lr = redQ[t] + redQ[32 + t] + redQ[64 + t] + redQ[96 + t];
        float la = redA[t] + redA[32 + t] + redA[64 + t] + redA[96 + t];
        float rn = clamp01(rel[b * NN + R0 + t]);
        float inv = 1.f / es;                     // es > 0 (diag edge kept)
        float fsum = rn * (0.6f * lr * inv + 0.4f * la);
        float nrm = 1.f / (fsum + 1e-8f);
        cfs[t] = make_float2(0.6f * inv * rn * nrm, 0.4f * rn * nrm);
    }
    // stage chunk0 into buffer 0, load chunk1 to regs
    *(uint4*)&sm.ck.Ks[0][krow0 * LQT + kseg] = rk0;
    *(uint4*)&sm.ck.Ks[0][krow1 * LQT + kseg] = rk1;
    *(uint4*)&sm.ck.Bs[0][bd0 * LPT + bsg] = rb0;
    *(uint4*)&sm.ck.Bs[0][bd1 * LPT + bsg] = rb1;
    rk0 = *(const uint4*)&Kg[(size_t)(64 + krow0) * DD + kseg];
    rk1 = *(const uint4*)&Kg[(size_t)(64 + krow1) * DD + kseg];
    rb0 = *(const uint4*)&Bg[(size_t)bd0 * NN + 64 + bsg];
    rb1 = *(const uint4*)&Bg[(size_t)bd1 * NN + 64 + bsg];
    __syncthreads();                  // buf0 + cfs ready

    // ======================= PASS 2: A_fuse + H GEMM ========================
    f32x4 acc[2];
    acc[0] = (f32x4){0.f, 0.f, 0.f, 0.f};
    acc[1] = (f32x4){0.f, 0.f, 0.f, 0.f};

    for (int ic = 0; ic < 32; ++ic) {
        const int p = ic & 1;
        const u16* Kc = sm.ck.Ks[p];
        u16* Kn = sm.ck.Ks[p ^ 1];
        const u16* Bc = sm.ck.Bs[p];
        u16* Bn = sm.ck.Bs[p ^ 1];
        if (ic + 1 < 32) {            // write chunk ic+1 to alt buffers
            *(uint4*)&Kn[krow0 * LQT + kseg] = rk0;
            *(uint4*)&Kn[krow1 * LQT + kseg] = rk1;
            *(uint4*)&Bn[bd0 * LPT + bsg] = rb0;
            *(uint4*)&Bn[bd1 * LPT + bsg] = rb1;
        }
        if (ic + 2 < 32) {            // prefetch chunk ic+2
            int kn2 = (ic + 2) * 64;
            rk0 = *(const uint4*)&Kg[(size_t)(kn2 + krow0) * DD + kseg];
            rk1 = *(const uint4*)&Kg[(size_t)(kn2 + krow1) * DD + kseg];
            rb0 = *(const uint4*)&Bg[(size_t)bd0 * NN + kn2 + bsg];
            rb1 = *(const uint4*)&Bg[(size_t)bd1 * NN + kn2 + bsg];
        }
        // ---- MFMA1: S chunk (identical fragment order to pass 1)
        f32x4 sa = (f32x4){0.f, 0.f, 0.f, 0.f};
        {
            const u16* kr = &Kc[(j2 * 16 + r16) * LQT + q * 8];
            bf16x8 b0 = *(const bf16x8*)&kr[0];
            sa = __builtin_amdgcn_mfma_f32_16x16x32_bf16(qf0, b0, sa, 0, 0, 0);
            b0 = *(const bf16x8*)&kr[32];
            sa = __builtin_amdgcn_mfma_f32_16x16x32_bf16(qf1, b0, sa, 0, 0, 0);
            b0 = *(const bf16x8*)&kr[64];
            sa = __builtin_amdgcn_mfma_f32_16x16x32_bf16(qf2, b0, sa, 0, 0, 0);
            b0 = *(const bf16x8*)&kr[96];
            sa = __builtin_amdgcn_mfma_f32_16x16x32_bf16(qf3, b0, sa, 0, 0, 0);
        }
        // ---- epilogue: e, A_fuse value, global store + bf16 to As
        int mb = ic * 64 + mloc;
        float rm = clamp01(rel[b * NN + mb]);
        float2 cf0 = cfs[wr + q * 4 + 0];
        float2 cf1 = cfs[wr + q * 4 + 1];
        float2 cf2 = cfs[wr + q * 4 + 2];
        float2 cf3 = cfs[wr + q * 4 + 3];
        float e0 = __expf(sa[0] + h2f((u16)(pl0 & 0xffff)));
        float v0 = rm * fmaf(e0, cf0.x, bf2f((u16)(pl0 >> 16)) * cf0.y);
        float e1 = __expf(sa[1] + h2f((u16)(pl1 & 0xffff)));
        float v1 = rm * fmaf(e1, cf1.x, bf2f((u16)(pl1 >> 16)) * cf1.y);
        float e2 = __expf(sa[2] + h2f((u16)(pl2 & 0xffff)));
        float v2 = rm * fmaf(e2, cf2.x, bf2f((u16)(pl2 >> 16)) * cf2.y);
        float e3 = __expf(sa[3] + h2f((u16)(pl3 & 0xffff)));
        float v3 = rm * fmaf(e3, cf3.x, bf2f((u16)(pl3 >> 16)) * cf3.y);
        size_t ob = ((size_t)b * NN + n0) * NN + mb;
        Af[ob] = v0;
        Af[ob + NN] = v1;
        Af[ob + 2 * NN] = v2;
        Af[ob + 3 * NN] = v3;
        sm.ck.As[(wr + q * 4 + 0) * LPT + mloc] = f2bf(v0);
        sm.ck.As[(wr + q * 4 + 1) * LPT + mloc] = f2bf(v1);
        sm.ck.As[(wr + q * 4 + 2) * LPT + mloc] = f2bf(v2);
        sm.ck.As[(wr + q * 4 + 3) * LPT + mloc] = f2bf(v3);
        if (ic + 1 < 32) {            // lam for chunk ic+1
            size_t lb = lb0 + (ic + 1) * 64;
            pl0 = lam[lb];
            pl1 = lam[lb + NN];
            pl2 = lam[lb + 2 * NN];
            pl3 = lam[lb + 3 * NN];
        }
        __syncthreads();              // barrier A: As + alt-buffer writes visible
        // ---- MFMA2: H += As @ Bc
#pragma unroll
        for (int kst = 0; kst < 2; ++kst) {
            int ko = kst * 32 + q * 8;
            bf16x8 a0 = *(const bf16x8*)&sm.ck.As[(wr + r16) * LPT + ko];
            bf16x8 b0 = *(const bf16x8*)&Bc[(wc + r16) * LPT + ko];
            bf16x8 b1v = *(const bf16x8*)&Bc[(wc + 16 + r16) * LPT + ko];
            acc[0] = __builtin_amdgcn_mfma_f32_16x16x32_bf16(a0, b0, acc[0], 0, 0, 0);
            acc[1] = __builtin_amdgcn_mfma_f32_16x16x32_bf16(a0, b1v, acc[1], 0, 0, 0);
        }
        __syncthreads();              // barrier B: MFMA2 reads drained
    }

    // ---- fused final: H -> bf16 LDS, @W_lin, relu, LN1, LN2 ----
#pragma unroll
    for (int rep = 0; rep < 4; ++rep) {
        int e = rep * 512 + t;        // 2048 uint4 slots
        int dp = e >> 4, seg = e & 15;
        *(uint4*)&sm.fin.Ws[dp * LWT + seg * 8] = *(const uint4*)&WlT[dp * DD + seg * 8];
    }
#pragma unroll
    for (int j = 0; j < 2; ++j)
#pragma unroll
        for (int r = 0; r < 4; ++r)
            sm.fin.Hs[(wr + q * 4 + r) * LWT + wc + j * 16 + r16] = f2bf(acc[j][r]);
    __syncthreads();

    f32x4 c2[2];
    c2[0] = (f32x4){0.f, 0.f, 0.f, 0.f};
    c2[1] = (f32x4){0.f, 0.f, 0.f, 0.f};
#pragma unroll
    for (int ksp = 0; ksp < 4; ++ksp) {
        int ko = ksp * 32 + q * 8;
        bf16x8 a0 = *(const bf16x8*)&sm.fin.Hs[(wr + r16) * LWT + ko];
        bf16x8 b0 = *(const bf16x8*)&sm.fin.Ws[(wc + r16) * LWT + ko];
        bf16x8 b1v = *(const bf16x8*)&sm.fin.Ws[(wc + 16 + r16) * LWT + ko];
        c2[0] = __builtin_amdgcn_mfma_f32_16x16x32_bf16(a0, b0, c2[0], 0, 0, 0);
        c2[1] = __builtin_amdgcn_mfma_f32_16x16x32_bf16(a0, b1v, c2[1], 0, 0, 0);
    }
    float v[2][4];
#pragma unroll
    for (int j = 0; j < 2; ++j)
#pragma unroll
        for (int r = 0; r < 4; ++r)
            v[j][r] = fmaxf(c2[j][r], 0.f);

    int c0 = wc + r16, c1 = wc + 16 + r16;
    float s1c0 = s1[c0], s1c1 = s1[c1], b1c0 = b1[c0], b1c1 = b1[c1];
    float s2c0 = s2[c0], s2c1 = s2[c1], b2c0 = b2[c0], b2c1 = b2[c1];
    int g4 = (w & 3) * 32;            // reduction group offset

#pragma unroll
    for (int r = 0; r < 4; ++r) {
        float s = v[0][r] + v[1][r];
        float qq = v[0][r] * v[0][r] + v[1][r] * v[1][r];
#pragma unroll
        for (int off = 1; off < 16; off <<= 1) {
            s += __shfl_xor(s, off);
            qq += __shfl_xor(qq, off);
        }
        if (r16 == 0) {
            int row = wr + q * 4 + r;
            redS[g4 + row] = s;
            redQ[g4 + row] = qq;
        }
    }
    __syncthreads();
    if (t < 32) {
        float s = redS[t] + redS[32 + t] + redS[64 + t] + redS[96 + t];
        float qq = redQ[t] + redQ[32 + t] + redQ[64 + t] + redQ[96 + t];
        float mu = s * (1.f / 128.f);
        float var = qq * (1.f / 128.f) - mu * mu;
        MV[t] = make_float2(mu, 1.f / sqrtf(var + 1e-5f));
    }
    __syncthreads();
    float y[2][4];
#pragma unroll
    for (int r = 0; r < 4; ++r) {
        float2 mv = MV[wr + q * 4 + r];
        y[0][r] = (v[0][r] - mv.x) * mv.y * s1c0 + b1c0;
        y[1][r] = (v[1][r] - mv.x) * mv.y * s1c1 + b1c1;
    }
    __syncthreads();
#pragma unroll
    for (int r = 0; r < 4; ++r) {
        float s = y[0][r] + y[1][r];
        float qq = y[0][r] * y[0][r] + y[1][r] * y[1][r];
#pragma unroll
        for (int off = 1; off < 16; off <<= 1) {
            s += __shfl_xor(s, off);
            qq += __shfl_xor(qq, off);
        }
        if (r16 == 0) {
            int row = wr + q * 4 + r;
            redS[g4 + row] = s;
            redQ[g4 + row] = qq;
        }
    }
    __syncthreads();
    if (t < 32) {
        float s = redS[t] + redS[32 + t] + redS[64 + t] + redS[96 + t];
        float qq = redQ[t] + redQ[32 + t] + redQ[64 + t] + redQ[96 + t];
        float mu = s * (1.f / 128.f);
        float var = qq * (1.f / 128.f) - mu * mu;
        MV[t] = make_float2(mu, 1.f / sqrtf(var + 1e-5f));
    }
    __syncthreads();
#pragma unroll
    for (int r = 0; r < 4; ++r) {
        float2 mv = MV[wr + q * 4 + r];
        size_t o = ((size_t)b * NN + R0 + wr + q * 4 + r) * DD;
        out[o + c0] = (y[0][r] - mv.x) * mv.y * s2c0 + b2c0;
        out[o + c1] = (y[1][r] - mv.x) * mv.y * s2c1 + b2c1;
    }
}

extern "C" void kernel_launch(void* const* d_in, const int* in_sizes, int n_in,
                              void* d_out, int out_size, void* d_ws, size_t ws_size,
                              hipStream_t stream) {
    const float* X = (const float*)d_in[0];
    const float* Msk = (const float*)d_in[1];
    const float* Astat = (const float*)d_in[2];
    const int* Mm = (const int*)d_in[3];
    const float* rel = (const float*)d_in[4];
    const float* Wproj = (const float*)d_in[5];
    const float* Wq = (const float*)d_in[6];
    const float* Wk = (const float*)d_in[7];
    const float* Wlin = (const float*)d_in[8];
    const float* s1 = (const float*)d_in[9];
    const float* b1 = (const float*)d_in[10];
    const float* s2 = (const float*)d_in[11];
    const float* b2 = (const float*)d_in[12];

    float* outMain = (float*)d_out;                       // (B,N,D)
    float* Afuse = outMain + (size_t)BB * NN * DD;        // (B,N,N)

    float* w_ = (float*)d_ws;
    float* Wpq = w_;                                      // 4096 f
    float* Wpk = w_ + 4096;                               // 4096 f
    u16* WlT = (u16*)(w_ + 8192);                         // 16384 u16
    u16* Qb = (u16*)(w_ + 16384);                         // 2097152 u16
    u16* Kb = (u16*)(w_ + 1064960);                       // 2097152 u16
    u16* HnT = (u16*)(w_ + 2113536);                      // 2097152 u16
    unsigned* lam = (unsigned*)(w_ + 3162112);            // 4194304 u32 (16 MB)

    prep_kernel<<<dim3(4192), dim3(256), 0, stream>>>(
        Astat, Mm, Wproj, Wq, Wk, Wlin, lam, Wpq, Wpk, WlT);
    proj3_kernel<<<dim3(512), dim3(256), 0, stream>>>(X, Msk, Wproj, Wpq, Wpk, HnT, Qb, Kb);

    prop_kernel<<<dim3(64, 8), dim3(512), 0, stream>>>(
        Qb, Kb, lam, rel, HnT, WlT, s1, b1, s2, b2, Afuse, outMain);
}